// Round 3
// baseline (526.211 us; speedup 1.0000x reference)
//
#include <hip/hip_runtime.h>
#include <cstdint>
#include <cstddef>

#define B_SZ 8
#define N1 4096
#define N2 256
#define LTOT 4352          // N1 + N2
#define DIMD 1024
#define HEADS 16
#define DH 64
#define MKV (B_SZ * LTOT)  // 34816
#define ATILE 64
#define AITERS (LTOT / ATILE)  // 68
#define G0_BLOCKS 4352         // 272 mt x 16 nt
#define MT_PER_XCD 34          // 272 / 8

typedef _Float16 f16;
typedef f16 f16x4_t __attribute__((ext_vector_type(4)));
typedef f16 f16x8_t __attribute__((ext_vector_type(8)));
typedef float f32x4_t __attribute__((ext_vector_type(4)));

// async global -> LDS, 16B per lane. LDS dest is wave-uniform base + lane*16.
__device__ __forceinline__ void g2l16(const void* g, void* l) {
  __builtin_amdgcn_global_load_lds(
      (__attribute__((address_space(1))) void*)g,
      (__attribute__((address_space(3))) void*)l, 16, 0, 0);
}

// T2 both-sides swizzle (rule #21): LDS rows are 64B (32 f16) = 4x 16B slots.
// Linear-read pattern (row stride 64B across 16 lanes) is an 8-way bank
// conflict. Fix: chunk c of row r lives at slot c ^ ((r>>1)&3). Staging
// pre-swizzles the per-lane GLOBAL chunk; reads apply the same XOR. Rows 0-7
// at a fixed read slot then cover all 8 bank-quads (2-way residual = free).

// ---------------------------------------------------------------------------
// Kernel 1: prep = layernorm/modulation (blocks 0..MKV-1) + weight casts
// ---------------------------------------------------------------------------
__global__ __launch_bounds__(256) void prep_kernel(
    const float* __restrict__ x, const float* __restrict__ lat,
    const float* __restrict__ shift, const float* __restrict__ scale,
    const float* __restrict__ ln1w, const float* __restrict__ ln1b,
    const float* __restrict__ ln2w, const float* __restrict__ ln2b,
    const float* __restrict__ Wq, const float* __restrict__ Wkv,
    const float* __restrict__ Wo, f16* __restrict__ kv_in,
    f16* __restrict__ Wq16, f16* __restrict__ Wkv16, f16* __restrict__ Wo16) {
  const int bid = blockIdx.x;
  const int tid = threadIdx.x;
  if (bid >= MKV) {  // weight casts: 1024 f32 per block
    const int c = bid - MKV;
    const float* src;
    f16* dst;
    int off;
    if (c < 1024) { src = Wq; dst = Wq16; off = c; }
    else if (c < 3072) { src = Wkv; dst = Wkv16; off = c - 1024; }
    else { src = Wo; dst = Wo16; off = c - 3072; }
    const int i = off * 256 + tid;
    float4 v = ((const float4*)src)[i];
    f16x4_t o = {(f16)v.x, (f16)v.y, (f16)v.z, (f16)v.w};
    ((f16x4_t*)dst)[i] = o;
    return;
  }
  const int row = bid;
  const int b = row / LTOT;
  const int n = row - b * LTOT;
  const bool is_lat = (n >= N1);
  const float* src = is_lat ? (lat + (size_t)(b * N2 + (n - N1)) * DIMD)
                            : (x + (size_t)(b * N1 + n) * DIMD);
  float4 v = ((const float4*)src)[tid];
  float s = v.x + v.y + v.z + v.w;
  float s2 = v.x * v.x + v.y * v.y + v.z * v.z + v.w * v.w;
#pragma unroll
  for (int m = 1; m <= 32; m <<= 1) {
    s += __shfl_xor(s, m, 64);
    s2 += __shfl_xor(s2, m, 64);
  }
  __shared__ float red[8];
  const int wave = tid >> 6;
  if ((tid & 63) == 0) { red[wave * 2] = s; red[wave * 2 + 1] = s2; }
  __syncthreads();
  s = red[0] + red[2] + red[4] + red[6];
  s2 = red[1] + red[3] + red[5] + red[7];
  const float mean = s * (1.0f / DIMD);
  const float var = fmaxf(s2 * (1.0f / DIMD) - mean * mean, 0.0f);
  const float rstd = rsqrtf(var + 1e-5f);
  const float4 w4 = ((const float4*)(is_lat ? ln2w : ln1w))[tid];
  const float4 b4 = ((const float4*)(is_lat ? ln2b : ln1b))[tid];
  float y0 = (v.x - mean) * rstd * w4.x + b4.x;
  float y1 = (v.y - mean) * rstd * w4.y + b4.y;
  float y2 = (v.z - mean) * rstd * w4.z + b4.z;
  float y3 = (v.w - mean) * rstd * w4.w + b4.w;
  if (is_lat) {
    float4 sc = ((const float4*)(scale + (size_t)b * DIMD))[tid];
    float4 sh = ((const float4*)(shift + (size_t)b * DIMD))[tid];
    y0 = y0 * (1.0f + sc.x) + sh.x;
    y1 = y1 * (1.0f + sc.y) + sh.y;
    y2 = y2 * (1.0f + sc.z) + sh.z;
    y3 = y3 * (1.0f + sc.w) + sh.w;
  }
  f16x4_t o = {(f16)y0, (f16)y1, (f16)y2, (f16)y3};
  *(f16x4_t*)(kv_in + (size_t)row * DIMD + tid * 4) = o;
}

// ---------------------------------------------------------------------------
// Kernel 2: fused pre-attention GEMMs (kv + q) in ONE dispatch.
// 128x128 tiles, BK=32, 16x16x32 f16 MFMA, XCD-swizzled kv blocks.
// Double-buffered LDS K-loop with raw vmcnt(4)/s_barrier (counted vmcnt=T4).
// R2: T2 both-sides XOR swizzle on As/Bs (8-way -> 2-way on ds_read_b128).
// ---------------------------------------------------------------------------
__global__ __launch_bounds__(256, 4) void gemm_pre(
    const f16* __restrict__ kv_in, const f16* __restrict__ Wkv16,
    const f16* __restrict__ Wq16, f16* __restrict__ kbuf,
    f16* __restrict__ vbuf, f16* __restrict__ qbuf) {
  const int id = blockIdx.x;
  const bool is_kv = (id < G0_BLOCKS);
  int mt, nt;
  const f16 *Abase, *Bbase;
  if (is_kv) {
    const int xcd = id & 7, l = id >> 3;
    mt = xcd * MT_PER_XCD + (l >> 4);
    nt = l & 15;
    Abase = kv_in + (size_t)mt * 128 * DIMD;
    Bbase = Wkv16 + (size_t)nt * 128 * DIMD;
  } else {
    const int id2 = id - G0_BLOCKS;
    mt = id2 >> 3;  // 0..15
    nt = id2 & 7;
    const int bb = mt >> 1;
    Abase = kv_in + ((size_t)(bb * LTOT + N1 + (mt & 1) * 128)) * DIMD;
    Bbase = Wq16 + (size_t)nt * 128 * DIMD;
  }
  __shared__ alignas(16) f16 As[2][128 * 32];
  __shared__ alignas(16) f16 Bs[2][128 * 32];
  const int tid = threadIdx.x;
  const int wave = tid >> 6, lane = tid & 63;
  const int wm = (wave & 1) * 64, wn = (wave >> 1) * 64;
  const int lrow = lane >> 2, lcol = (lane & 3) * 8;
  const int r16 = lane & 15, g8 = (lane >> 4) * 8, q4 = (lane >> 4) * 4;
  // T2 swizzle terms: source chunk permutation + matching read-slot XOR
  const int lcol_sw = (((lane & 3) ^ ((lrow >> 1) & 3)) * 8);
  const int g8sw = (((lane >> 4) ^ ((r16 >> 1) & 3)) * 8);
  (void)lcol; (void)g8;
  f32x4_t acc[4][4] = {};

  // 4 g2l16 per wave per tile (global source chunk pre-swizzled)
  auto stage = [&](int k0, int buf) {
    g2l16(Abase + (size_t)(wave * 16 + lrow) * DIMD + k0 + lcol_sw, &As[buf][(wave * 16) * 32]);
    g2l16(Abase + (size_t)(64 + wave * 16 + lrow) * DIMD + k0 + lcol_sw, &As[buf][(64 + wave * 16) * 32]);
    g2l16(Bbase + (size_t)(wave * 16 + lrow) * DIMD + k0 + lcol_sw, &Bs[buf][(wave * 16) * 32]);
    g2l16(Bbase + (size_t)(64 + wave * 16 + lrow) * DIMD + k0 + lcol_sw, &Bs[buf][(64 + wave * 16) * 32]);
  };
  auto body = [&](int kt, int cur) {
    if (kt < 31) asm volatile("s_waitcnt vmcnt(4)" ::: "memory");  // tile kt landed
    else         asm volatile("s_waitcnt vmcnt(0)" ::: "memory");  // final tile
    asm volatile("s_barrier" ::: "memory");
    f16x8_t a[4], bf[4];
#pragma unroll
    for (int i = 0; i < 4; i++)
      a[i] = *(const f16x8_t*)&As[cur][(wm + i * 16 + r16) * 32 + g8sw];
#pragma unroll
    for (int j = 0; j < 4; j++)
      bf[j] = *(const f16x8_t*)&Bs[cur][(wn + j * 16 + r16) * 32 + g8sw];
#pragma unroll
    for (int i = 0; i < 4; i++)
#pragma unroll
      for (int j = 0; j < 4; j++)
        acc[i][j] = __builtin_amdgcn_mfma_f32_16x16x32_f16(a[i], bf[j], acc[i][j], 0, 0, 0);
    asm volatile("s_waitcnt lgkmcnt(0)" ::: "memory");  // buf[cur] reads done
    asm volatile("s_barrier" ::: "memory");
    if (kt + 2 < 32) stage((kt + 2) * 32, cur);  // refill buf[cur]
  };
  stage(0, 0);
  stage(32, 1);
#pragma unroll 1
  for (int kt = 0; kt < 32; kt += 2) { body(kt, 0); body(kt + 1, 1); }

  if (is_kv) {
    const int m0 = mt * 128;
    const int b = m0 / LTOT;
    const int n0 = m0 - b * LTOT;
    const int e0 = nt * 128;
    if (e0 < 1024) {  // k half: ((b*16+h)*4352 + n)*64 + d
#pragma unroll
      for (int i = 0; i < 4; i++) {
        const int n_base = n0 + wm + i * 16 + q4;
#pragma unroll
        for (int j = 0; j < 4; j++) {
          const int e = e0 + wn + j * 16 + r16;
          const int h = e >> 6, d = e & 63;
          const size_t base = ((size_t)(b * HEADS + h) * LTOT);
#pragma unroll
          for (int r = 0; r < 4; r++)
            kbuf[(base + n_base + r) * DH + d] = (f16)acc[i][j][r];
        }
      }
    } else {  // v half, transposed: ((b*16+h)*64 + d)*4352 + n
      const int e0v = e0 - 1024;
#pragma unroll
      for (int i = 0; i < 4; i++) {
        const int n_base = n0 + wm + i * 16 + q4;
#pragma unroll
        for (int j = 0; j < 4; j++) {
          const int e = e0v + wn + j * 16 + r16;
          const int h = e >> 6, d = e & 63;
          f16x4_t pk = {(f16)acc[i][j][0], (f16)acc[i][j][1],
                        (f16)acc[i][j][2], (f16)acc[i][j][3]};
          *(f16x4_t*)&vbuf[((size_t)(b * HEADS + h) * DH + d) * LTOT + n_base] = pk;
        }
      }
    }
  } else {  // q: ((b*16+h)*256 + n)*64 + d
    const int b = mt >> 1;
#pragma unroll
    for (int i = 0; i < 4; i++) {
      const int n_base = (mt & 1) * 128 + wm + i * 16 + q4;
#pragma unroll
      for (int j = 0; j < 4; j++) {
        const int e = nt * 128 + wn + j * 16 + r16;
        const int h = e >> 6, d = e & 63;
#pragma unroll
        for (int r = 0; r < 4; r++)
          qbuf[((size_t)(b * HEADS + h) * N2 + n_base + r) * DH + d] = (f16)acc[i][j][r];
      }
    }
  }
}

// ---------------------------------------------------------------------------
// Kernel 3: out GEMM -> f32 d_out. 128x64 tiles (256 blocks = 1/CU) + same
// dbuf/vmcnt pipelined K-loop. R2: same T2 swizzle as gemm_pre.
// ---------------------------------------------------------------------------
__global__ __launch_bounds__(256) void gemm_out(
    const f16* __restrict__ A0, const f16* __restrict__ BT,
    float* __restrict__ outp) {
  const int id = blockIdx.x;
  const int mt = id >> 4, nt = id & 15;
  const f16* Abase = A0 + (size_t)mt * 128 * DIMD;
  const f16* Bbase = BT + (size_t)nt * 64 * DIMD;
  __shared__ alignas(16) f16 As[2][128 * 32];
  __shared__ alignas(16) f16 Bs[2][64 * 32];
  const int tid = threadIdx.x;
  const int wave = tid >> 6, lane = tid & 63;
  const int wm = (wave & 1) * 64, wn = (wave >> 1) * 32;
  const int lrow = lane >> 2, lcol = (lane & 3) * 8;
  const int r16 = lane & 15, g8 = (lane >> 4) * 8, q4 = (lane >> 4) * 4;
  const int lcol_sw = (((lane & 3) ^ ((lrow >> 1) & 3)) * 8);
  const int g8sw = (((lane >> 4) ^ ((r16 >> 1) & 3)) * 8);
  (void)lcol; (void)g8;
  f32x4_t acc[4][2] = {};

  // 3 g2l16 per wave per tile (A 2 chunks, B 1 chunk)
  auto stage = [&](int k0, int buf) {
    g2l16(Abase + (size_t)(wave * 16 + lrow) * DIMD + k0 + lcol_sw, &As[buf][(wave * 16) * 32]);
    g2l16(Abase + (size_t)(64 + wave * 16 + lrow) * DIMD + k0 + lcol_sw, &As[buf][(64 + wave * 16) * 32]);
    g2l16(Bbase + (size_t)(wave * 16 + lrow) * DIMD + k0 + lcol_sw, &Bs[buf][(wave * 16) * 32]);
  };
  auto body = [&](int kt, int cur) {
    if (kt < 31) asm volatile("s_waitcnt vmcnt(3)" ::: "memory");
    else         asm volatile("s_waitcnt vmcnt(0)" ::: "memory");
    asm volatile("s_barrier" ::: "memory");
    f16x8_t a[4], bf[2];
#pragma unroll
    for (int i = 0; i < 4; i++)
      a[i] = *(const f16x8_t*)&As[cur][(wm + i * 16 + r16) * 32 + g8sw];
#pragma unroll
    for (int j = 0; j < 2; j++)
      bf[j] = *(const f16x8_t*)&Bs[cur][(wn + j * 16 + r16) * 32 + g8sw];
#pragma unroll
    for (int i = 0; i < 4; i++)
#pragma unroll
      for (int j = 0; j < 2; j++)
        acc[i][j] = __builtin_amdgcn_mfma_f32_16x16x32_f16(a[i], bf[j], acc[i][j], 0, 0, 0);
    asm volatile("s_waitcnt lgkmcnt(0)" ::: "memory");
    asm volatile("s_barrier" ::: "memory");
    if (kt + 2 < 32) stage((kt + 2) * 32, cur);
  };
  stage(0, 0);
  stage(32, 1);
#pragma unroll 1
  for (int kt = 0; kt < 32; kt += 2) { body(kt, 0); body(kt + 1, 1); }

  const int m0 = mt * 128, n0 = nt * 64;
#pragma unroll
  for (int i = 0; i < 4; i++) {
#pragma unroll
    for (int j = 0; j < 2; j++) {
      const int col = n0 + wn + j * 16 + r16;
#pragma unroll
      for (int r = 0; r < 4; r++)
        outp[(size_t)(m0 + wm + i * 16 + q4 + r) * DIMD + col] = acc[i][j][r];
    }
  }
}

// ---------------------------------------------------------------------------
// Kernel 4: flash attention — 512 threads (8 waves), K-tile 64, depth-2 async
// K/V double-buffer with raw vmcnt/s_barrier. (512,2). R1: pair swizzle,
// defer-max, setprio. R2: T2 swizzle on Ks/Vs/QP (same 8-way pattern as the
// GEMMs). Ps layout (72-half stride) already conflict-free — untouched.
// ---------------------------------------------------------------------------
__global__ __launch_bounds__(512, 2) void attn_kernel(
    const f16* __restrict__ qbuf, const f16* __restrict__ kbuf,
    const f16* __restrict__ vbuf, f16* __restrict__ attn_out) {
  const int bh = blockIdx.x & 127;   // pair swizzle: bid, bid+128 -> same XCD
  const int qt = blockIdx.x >> 7;
  const int b = bh >> 4, h = bh & 15;
  const f16* qg = qbuf + ((size_t)bh * N2 + qt * 128) * DH;
  const f16* kg = kbuf + (size_t)bh * LTOT * DH;
  const f16* vg = vbuf + (size_t)bh * DH * LTOT;

  __shared__ alignas(16) f16 Ks[2][4096];  // 2 bufs x (2 d-panels x 64k x 32)
  __shared__ alignas(16) f16 Vs[2][4096];  // 2 bufs x (2 k-panels x 64d x 32)
  __shared__ alignas(16) f16 QP[9216];     // Q (8192, prologue) / P (per-wave)

  const int tid = threadIdx.x, wave = tid >> 6, lane = tid & 63;
  const int lrow = lane >> 2, lcol = (lane & 3) * 8;
  const int r16 = lane & 15, g8 = (lane >> 4) * 8, q4 = (lane >> 4) * 4;
  const int lcol_sw = (((lane & 3) ^ ((lrow >> 1) & 3)) * 8);
  const int g8sw = (((lane >> 4) ^ ((r16 >> 1) & 3)) * 8);
  (void)lcol;
  f16* Ps = &QP[wave * 1152];  // 16 q-rows x 72 halves, wave-private

  // prologue: stage Q (2 chunks/wave), source chunk pre-swizzled
#pragma unroll
  for (int i = 0; i < 2; i++) {
    const int c = wave * 2 + i, s = c >> 3, rb = (c & 7) * 16;
    g2l16(qg + (size_t)(rb + lrow) * DH + s * 32 + lcol_sw, &QP[s * 4096 + rb * 32]);
  }
  auto stage = [&](int kt, int buf) {
    const int s = wave >> 2, rb = (wave & 3) * 16;
    g2l16(kg + (size_t)(kt * ATILE + rb + lrow) * DH + s * 32 + lcol_sw,
          &Ks[buf][s * 2048 + rb * 32]);
    g2l16(vg + (size_t)(rb + lrow) * LTOT + kt * ATILE + s * 32 + lcol_sw,
          &Vs[buf][s * 2048 + rb * 32]);
  };
  stage(0, 0);
  stage(1, 1);
  asm volatile("s_waitcnt vmcnt(4)" ::: "memory");  // Q (oldest 2) landed
  asm volatile("s_barrier" ::: "memory");
  f16x8_t bQ[2];
#pragma unroll
  for (int s = 0; s < 2; s++)
    bQ[s] = *(const f16x8_t*)&QP[s * 4096 + (wave * 16 + r16) * 32 + g8sw];
  asm volatile("s_waitcnt lgkmcnt(0)" ::: "memory");  // bQ in regs before P overlays Q

  f32x4_t oacc[4] = {};
  float mrow = -1e30f, lsum = 0.0f;
  const float SCL = 0.125f * 1.44269504089f;  // attn_scale^2 * log2(e)

  for (int kt = 0; kt < AITERS; kt++) {
    const int cur = kt & 1;
    asm volatile("s_waitcnt vmcnt(2)" ::: "memory");  // buf[cur] landed; next in flight
    asm volatile("s_barrier" ::: "memory");
    f32x4_t sacc[4] = {};
    __builtin_amdgcn_s_setprio(1);
#pragma unroll
    for (int s = 0; s < 2; s++) {
      f16x8_t aK[4];
#pragma unroll
      for (int i = 0; i < 4; i++)
        aK[i] = *(const f16x8_t*)&Ks[cur][s * 2048 + (i * 16 + r16) * 32 + g8sw];
#pragma unroll
      for (int i = 0; i < 4; i++)
        sacc[i] = __builtin_amdgcn_mfma_f32_16x16x32_f16(aK[i], bQ[s], sacc[i], 0, 0, 0);
    }
    __builtin_amdgcn_s_setprio(0);
    float vmax = -1e30f;
#pragma unroll
    for (int i = 0; i < 4; i++)
#pragma unroll
      for (int r = 0; r < 4; r++) vmax = fmaxf(vmax, sacc[i][r]);
    vmax = fmaxf(vmax, __shfl_xor(vmax, 16, 64));
    vmax = fmaxf(vmax, __shfl_xor(vmax, 32, 64));
    // T13 defer-max: only rescale when some row's max grew by >8 (log2 units).
    const float pm = SCL * vmax;
    if (!__all(pm <= mrow + 8.0f)) {
      const float m_new = fmaxf(mrow, pm);
      const float alpha = exp2f(mrow - m_new);
      lsum *= alpha;
#pragma unroll
      for (int id = 0; id < 4; id++) oacc[id] *= alpha;
      mrow = m_new;
    }
    float psum = 0.0f;
#pragma unroll
    for (int i = 0; i < 4; i++) {
      f16x4_t pk;
#pragma unroll
      for (int r = 0; r < 4; r++) {
        const float p = exp2f(SCL * sacc[i][r] - mrow);
        psum += p;
        pk[r] = (f16)p;
      }
      *(f16x4_t*)&Ps[r16 * 72 + i * 16 + q4] = pk;
    }
    psum += __shfl_xor(psum, 16, 64);
    psum += __shfl_xor(psum, 32, 64);
    lsum += psum;
    __builtin_amdgcn_s_setprio(1);
#pragma unroll
    for (int s2 = 0; s2 < 2; s2++) {
      f16x8_t aV[4];
#pragma unroll
      for (int id = 0; id < 4; id++)
        aV[id] = *(const f16x8_t*)&Vs[cur][s2 * 2048 + (id * 16 + r16) * 32 + g8sw];
      const f16x8_t bP = *(const f16x8_t*)&Ps[r16 * 72 + s2 * 32 + g8];
#pragma unroll
      for (int id = 0; id < 4; id++)
        oacc[id] = __builtin_amdgcn_mfma_f32_16x16x32_f16(aV[id], bP, oacc[id], 0, 0, 0);
    }
    __builtin_amdgcn_s_setprio(0);
    asm volatile("s_waitcnt lgkmcnt(0)" ::: "memory");
    asm volatile("s_barrier" ::: "memory");
    if (kt + 2 < AITERS) stage(kt + 2, cur);
  }
  const float inv = 1.0f / lsum;
  const int q = qt * 128 + wave * 16 + r16;
  const size_t rowbase = ((size_t)(b * N2 + q)) * DIMD + h * DH;
#pragma unroll
  for (int id = 0; id < 4; id++) {
    f16x4_t pk;
#pragma unroll
    for (int r = 0; r < 4; r++) pk[r] = (f16)(oacc[id][r] * inv);
    *(f16x4_t*)&attn_out[rowbase + id * 16 + q4] = pk;
  }
}

// ---------------------------------------------------------------------------
extern "C" void kernel_launch(void* const* d_in, const int* in_sizes, int n_in,
                              void* d_out, int out_size, void* d_ws, size_t ws_size,
                              hipStream_t stream) {
  const float* x     = (const float*)d_in[0];
  const float* lat   = (const float*)d_in[1];
  const float* shift = (const float*)d_in[2];
  const float* scale = (const float*)d_in[3];
  const float* ln1w  = (const float*)d_in[4];
  const float* ln1b  = (const float*)d_in[5];
  const float* ln2w  = (const float*)d_in[6];
  const float* ln2b  = (const float*)d_in[7];
  const float* Wq    = (const float*)d_in[8];
  const float* Wkv   = (const float*)d_in[9];
  const float* Wo    = (const float*)d_in[10];
  float* outp = (float*)d_out;

  char* ws = (char*)d_ws;
  f16* kv_in = (f16*)ws;                 ws += (size_t)MKV * DIMD * 2;          // 68 MB
  f16* Wq16  = (f16*)ws;                 ws += (size_t)1024 * 1024 * 2;         // 2 MB
  f16* Wkv16 = (f16*)ws;                 ws += (size_t)2048 * 1024 * 2;         // 4 MB
  f16* Wo16  = (f16*)ws;                 ws += (size_t)1024 * 1024 * 2;         // 2 MB
  f16* qbuf  = (f16*)ws;                 ws += (size_t)B_SZ * HEADS * N2 * DH * 2;   // 4 MB
  f16* kbuf  = (f16*)ws;                 ws += (size_t)B_SZ * HEADS * LTOT * DH * 2; // 68 MB
  f16* vbuf  = (f16*)ws;                 ws += (size_t)B_SZ * HEADS * LTOT * DH * 2; // 68 MB
  f16* aout  = (f16*)ws;                 ws += (size_t)B_SZ * N2 * DIMD * 2;         // 4 MB

  prep_kernel<<<dim3(MKV + 4096), dim3(256), 0, stream>>>(
      x, lat, shift, scale, ln1w, ln1b, ln2w, ln2b, Wq, Wkv, Wo,
      kv_in, Wq16, Wkv16, Wo16);
  gemm_pre<<<dim3(G0_BLOCKS + 128), dim3(256), 0, stream>>>(
      kv_in, Wkv16, Wq16, kbuf, vbuf, qbuf);
  attn_kernel<<<dim3(256), dim3(512), 0, stream>>>(qbuf, kbuf, vbuf, aout);
  gemm_out<<<dim3(256), dim3(256), 0, stream>>>(aout, Wo16, outp);
}

// Round 4
// 523.702 us; speedup vs baseline: 1.0048x; 1.0048x over previous
//
#include <hip/hip_runtime.h>
#include <cstdint>
#include <cstddef>

#define B_SZ 8
#define N1 4096
#define N2 256
#define LTOT 4352          // N1 + N2
#define DIMD 1024
#define HEADS 16
#define DH 64
#define MKV (B_SZ * LTOT)  // 34816
#define ATILE 64
#define AITERS (LTOT / ATILE)  // 68
#define G0B 1088               // KV blocks: 136 mt x 8 nt (256x256 tiles)

typedef _Float16 f16;
typedef f16 f16x4_t __attribute__((ext_vector_type(4)));
typedef f16 f16x8_t __attribute__((ext_vector_type(8)));
typedef float f32x4_t __attribute__((ext_vector_type(4)));

// async global -> LDS, 16B per lane. LDS dest is wave-uniform base + lane*16.
__device__ __forceinline__ void g2l16(const void* g, void* l) {
  __builtin_amdgcn_global_load_lds(
      (__attribute__((address_space(1))) void*)g,
      (__attribute__((address_space(3))) void*)l, 16, 0, 0);
}

// ---------------------------------------------------------------------------
// Kernel 1: prep = layernorm/modulation (blocks 0..MKV-1) + weight casts
// ---------------------------------------------------------------------------
__global__ __launch_bounds__(256) void prep_kernel(
    const float* __restrict__ x, const float* __restrict__ lat,
    const float* __restrict__ shift, const float* __restrict__ scale,
    const float* __restrict__ ln1w, const float* __restrict__ ln1b,
    const float* __restrict__ ln2w, const float* __restrict__ ln2b,
    const float* __restrict__ Wq, const float* __restrict__ Wkv,
    const float* __restrict__ Wo, f16* __restrict__ kv_in,
    f16* __restrict__ Wq16, f16* __restrict__ Wkv16, f16* __restrict__ Wo16) {
  const int bid = blockIdx.x;
  const int tid = threadIdx.x;
  if (bid >= MKV) {  // weight casts: 1024 f32 per block
    const int c = bid - MKV;
    const float* src;
    f16* dst;
    int off;
    if (c < 1024) { src = Wq; dst = Wq16; off = c; }
    else if (c < 3072) { src = Wkv; dst = Wkv16; off = c - 1024; }
    else { src = Wo; dst = Wo16; off = c - 3072; }
    const int i = off * 256 + tid;
    float4 v = ((const float4*)src)[i];
    f16x4_t o = {(f16)v.x, (f16)v.y, (f16)v.z, (f16)v.w};
    ((f16x4_t*)dst)[i] = o;
    return;
  }
  const int row = bid;
  const int b = row / LTOT;
  const int n = row - b * LTOT;
  const bool is_lat = (n >= N1);
  const float* src = is_lat ? (lat + (size_t)(b * N2 + (n - N1)) * DIMD)
                            : (x + (size_t)(b * N1 + n) * DIMD);
  float4 v = ((const float4*)src)[tid];
  float s = v.x + v.y + v.z + v.w;
  float s2 = v.x * v.x + v.y * v.y + v.z * v.z + v.w * v.w;
#pragma unroll
  for (int m = 1; m <= 32; m <<= 1) {
    s += __shfl_xor(s, m, 64);
    s2 += __shfl_xor(s2, m, 64);
  }
  __shared__ float red[8];
  const int wave = tid >> 6;
  if ((tid & 63) == 0) { red[wave * 2] = s; red[wave * 2 + 1] = s2; }
  __syncthreads();
  s = red[0] + red[2] + red[4] + red[6];
  s2 = red[1] + red[3] + red[5] + red[7];
  const float mean = s * (1.0f / DIMD);
  const float var = fmaxf(s2 * (1.0f / DIMD) - mean * mean, 0.0f);
  const float rstd = rsqrtf(var + 1e-5f);
  const float4 w4 = ((const float4*)(is_lat ? ln2w : ln1w))[tid];
  const float4 b4 = ((const float4*)(is_lat ? ln2b : ln1b))[tid];
  float y0 = (v.x - mean) * rstd * w4.x + b4.x;
  float y1 = (v.y - mean) * rstd * w4.y + b4.y;
  float y2 = (v.z - mean) * rstd * w4.z + b4.z;
  float y3 = (v.w - mean) * rstd * w4.w + b4.w;
  if (is_lat) {
    float4 sc = ((const float4*)(scale + (size_t)b * DIMD))[tid];
    float4 sh = ((const float4*)(shift + (size_t)b * DIMD))[tid];
    y0 = y0 * (1.0f + sc.x) + sh.x;
    y1 = y1 * (1.0f + sc.y) + sh.y;
    y2 = y2 * (1.0f + sc.z) + sh.z;
    y3 = y3 * (1.0f + sc.w) + sh.w;
  }
  f16x4_t o = {(f16)y0, (f16)y1, (f16)y2, (f16)y3};
  *(f16x4_t*)(kv_in + (size_t)row * DIMD + tid * 4) = o;
}

// ---------------------------------------------------------------------------
// Kernel 2: fused pre-attention GEMMs (kv + q), R3: 8-phase 256x256 template
// (T3+T4+T2+T5). BK=64, 8 waves (2Mx4N), wave tile 128x64, acc[8][4].
// LDS 128KB: As/Bs[2 dbuf][2 half][128x64 f16]. A-half(mh) = quadrant rows
// {mh*64..+64} of both wrow stripes; B-half(nh) = nh stripes of all wcol.
// Per phase: ds_read subtile || stage 1 half-tile (2 g2l16) -> barrier ->
// lgkmcnt(0) -> setprio(1) 16 MFMA setprio(0) -> barrier.
// Counted vmcnt(4) ONLY at phases 3 and 7 (12 in flight, allow 4 youngest).
// Swizzle: 128B rows, chunk c stored at c^(row&7), both sides (rule #21).
// Stage schedule (iter i): p0 K(2i+1).A1  p1 K(2i+1).B0  p2 K(2i+2).A0
// p3 K(2i+2).B1  p4 K(2i+2).A1  p5 K(2i+2).B0  p6 K(2i+3).A0  p7 K(2i+3).B1
// (each half staged strictly after its last read; verified per-phase).
// ---------------------------------------------------------------------------
#define DS_A(buf, mh)                                                          \
  _Pragma("unroll") for (int i_ = 0; i_ < 4; i_++)                             \
  _Pragma("unroll") for (int ks_ = 0; ks_ < 2; ks_++)                          \
      aF[i_][ks_] = *(const f16x8_t*)&As[buf][mh][                             \
          (wrow * 64 + i_ * 16 + r16) * 64 + (((ks_ * 4 + g8i) ^ xk) * 8)];

#define DS_B(dst, buf, nh)                                                     \
  _Pragma("unroll") for (int j_ = 0; j_ < 2; j_++)                             \
  _Pragma("unroll") for (int ks_ = 0; ks_ < 2; ks_++)                          \
      dst[j_][ks_] = *(const f16x8_t*)&Bs[buf][nh][                            \
          (wcol * 32 + j_ * 16 + r16) * 64 + (((ks_ * 4 + g8i) ^ xk) * 8)];

#define MFMA16(mh, nh, BF)                                                     \
  __builtin_amdgcn_s_setprio(1);                                               \
  _Pragma("unroll") for (int ks_ = 0; ks_ < 2; ks_++)                          \
  _Pragma("unroll") for (int i_ = 0; i_ < 4; i_++)                             \
  _Pragma("unroll") for (int j_ = 0; j_ < 2; j_++)                             \
      acc[(mh)*4 + i_][(nh)*2 + j_] = __builtin_amdgcn_mfma_f32_16x16x32_f16(  \
          aF[i_][ks_], BF[j_][ks_], acc[(mh)*4 + i_][(nh)*2 + j_], 0, 0, 0);   \
  __builtin_amdgcn_s_setprio(0);

#define BARR asm volatile("s_barrier" ::: "memory")
#define LGKM0 asm volatile("s_waitcnt lgkmcnt(0)" ::: "memory")
#define VM4 asm volatile("s_waitcnt vmcnt(4)" ::: "memory")

__global__ __launch_bounds__(512, 2) void gemm_pre(
    const f16* __restrict__ kv_in, const f16* __restrict__ Wkv16,
    const f16* __restrict__ Wq16, f16* __restrict__ kbuf,
    f16* __restrict__ vbuf, f16* __restrict__ qbuf) {
  const int id = blockIdx.x;
  const bool is_kv = (id < G0B);
  int mt = 0, nt;
  const f16 *Abase, *Bbase;
  if (is_kv) {
    const int xcd = id & 7, l = id >> 3;   // 1088 = 8 * 136, bijective
    mt = xcd * 17 + (l >> 3);              // 136 mt, 17 per XCD
    nt = l & 7;
    Abase = kv_in + (size_t)mt * 256 * DIMD;
    Bbase = Wkv16 + (size_t)nt * 256 * DIMD;
  } else {
    const int id2 = id - G0B;
    const int bq = id2 >> 2;               // batch 0..7
    nt = id2 & 3;
    Abase = kv_in + ((size_t)(bq * LTOT + N1)) * DIMD;
    Bbase = Wq16 + (size_t)nt * 256 * DIMD;
  }
  __shared__ alignas(16) f16 As[2][2][128 * 64];
  __shared__ alignas(16) f16 Bs[2][2][128 * 64];
  const int tid = threadIdx.x;
  const int wave = tid >> 6, lane = tid & 63;
  const int wrow = wave >> 2, wcol = wave & 3;
  const int r16 = lane & 15, g8i = lane >> 4, q4 = (lane >> 4) * 4;
  const int xk = r16 & 7;
  const int t8 = tid >> 3, c8 = tid & 7;
  f32x4_t acc[8][4] = {};
  f16x8_t aF[4][2], b0F[2][2], b1F[2][2];

  // stage one A-half: rows {stripe*128 + mh*64 + [0,64)}, 2 rounds x 8KB
  auto stageA = [&](int kt, int buf, int mh) {
#pragma unroll
    for (int j = 0; j < 2; j++) {
      const int rih = j * 64 + t8;                      // LDS row in half
      const int row_g = j * 128 + mh * 64 + t8;         // global row in tile
      const int col8 = (c8 ^ (rih & 7)) * 8;            // inverse-swz source
      g2l16(Abase + (size_t)row_g * DIMD + kt * 64 + col8,
            &As[buf][mh][(j * 512 + wave * 64) * 8]);
    }
  };
  // stage one B-half: rows {wc*64 + nh*32 + [0,32)} for wc=0..3
  auto stageB = [&](int kt, int buf, int nh) {
#pragma unroll
    for (int j = 0; j < 2; j++) {
      const int rih = j * 64 + t8;
      const int row_g = (rih >> 5) * 64 + nh * 32 + (rih & 31);
      const int col8 = (c8 ^ (rih & 7)) * 8;
      g2l16(Bbase + (size_t)row_g * DIMD + kt * 64 + col8,
            &Bs[buf][nh][(j * 512 + wave * 64) * 8]);
    }
  };

  // prologue: K0 all 4 halves + K1 {A0, B1}; vmcnt(4) => K0 landed
  stageA(0, 0, 0); stageB(0, 0, 1); stageA(0, 0, 1); stageB(0, 0, 0);
  stageA(1, 1, 0); stageB(1, 1, 1);
  VM4; BARR;

#pragma unroll 1
  for (int it = 0; it < 8; ++it) {
    const int kA = 2 * it + 1;
    const int kB = (2 * it + 2 > 15) ? 15 : 2 * it + 2;  // clamp: dead-staged
    const int kC = (2 * it + 3 > 15) ? 15 : 2 * it + 3;
    // p0: quadrant (0,0) of buf0
    DS_A(0, 0); DS_B(b0F, 0, 0);
    stageA(kA, 1, 1);
    BARR; LGKM0; MFMA16(0, 0, b0F); BARR;
    // p1: (0,1)
    DS_B(b1F, 0, 1);
    stageB(kA, 1, 0);
    BARR; LGKM0; MFMA16(0, 1, b1F); BARR;
    // p2: (1,1)
    DS_A(0, 1);
    stageA(kB, 0, 0);
    BARR; LGKM0; MFMA16(1, 1, b1F); BARR;
    // p3: (1,0) — no ds_reads; vmcnt(4) covers buf1 (K 2i+1) for p4-7
    stageB(kB, 0, 1);
    VM4;
    BARR; LGKM0; MFMA16(1, 0, b0F); BARR;
    // p4: (0,0) of buf1
    DS_A(1, 0); DS_B(b0F, 1, 0);
    stageA(kB, 0, 1);
    BARR; LGKM0; MFMA16(0, 0, b0F); BARR;
    // p5: (0,1)
    DS_B(b1F, 1, 1);
    stageB(kB, 0, 0);
    BARR; LGKM0; MFMA16(0, 1, b1F); BARR;
    // p6: (1,1)
    DS_A(1, 1);
    stageA(kC, 1, 0);
    BARR; LGKM0; MFMA16(1, 1, b1F); BARR;
    // p7: (1,0); vmcnt(4) covers buf0 (K 2i+2) for next iter p0-3
    stageB(kC, 1, 1);
    VM4;
    BARR; LGKM0; MFMA16(1, 0, b0F); BARR;
  }
  asm volatile("s_waitcnt vmcnt(0)" ::: "memory");  // drain dead stages

  if (is_kv) {
    const int m0 = mt * 256;
    const int b = m0 / LTOT;
    const int n0 = m0 - b * LTOT;
    if (nt < 4) {  // k half: ((b*16+h)*4352 + n)*64 + d
#pragma unroll
      for (int ai = 0; ai < 8; ai++) {
        const int n_base = n0 + wrow * 128 + (ai >> 2) * 64 + (ai & 3) * 16 + q4;
#pragma unroll
        for (int bj = 0; bj < 4; bj++) {
          const int e = nt * 256 + wcol * 64 + (bj >> 1) * 32 + (bj & 1) * 16 + r16;
          const int h = e >> 6, d = e & 63;
          const size_t base = (size_t)(b * HEADS + h) * LTOT;
#pragma unroll
          for (int r = 0; r < 4; r++)
            kbuf[(base + n_base + r) * DH + d] = (f16)acc[ai][bj][r];
        }
      }
    } else {  // v half, transposed: ((b*16+h)*64 + d)*4352 + n
#pragma unroll
      for (int ai = 0; ai < 8; ai++) {
        const int n_base = n0 + wrow * 128 + (ai >> 2) * 64 + (ai & 3) * 16 + q4;
#pragma unroll
        for (int bj = 0; bj < 4; bj++) {
          const int e = (nt - 4) * 256 + wcol * 64 + (bj >> 1) * 32 + (bj & 1) * 16 + r16;
          const int h = e >> 6, d = e & 63;
          f16x4_t pk = {(f16)acc[ai][bj][0], (f16)acc[ai][bj][1],
                        (f16)acc[ai][bj][2], (f16)acc[ai][bj][3]};
          *(f16x4_t*)&vbuf[((size_t)(b * HEADS + h) * DH + d) * LTOT + n_base] = pk;
        }
      }
    }
  } else {  // q: ((b*16+h)*256 + n)*64 + d
    const int b = (id - G0B) >> 2;
#pragma unroll
    for (int ai = 0; ai < 8; ai++) {
      const int qn = wrow * 128 + (ai >> 2) * 64 + (ai & 3) * 16 + q4;
#pragma unroll
      for (int bj = 0; bj < 4; bj++) {
        const int e = nt * 256 + wcol * 64 + (bj >> 1) * 32 + (bj & 1) * 16 + r16;
        const int h = e >> 6, d = e & 63;
#pragma unroll
        for (int r = 0; r < 4; r++)
          qbuf[((size_t)(b * HEADS + h) * N2 + qn + r) * DH + d] = (f16)acc[ai][bj][r];
      }
    }
  }
}

// ---------------------------------------------------------------------------
// Kernel 3: out GEMM -> f32 d_out. 128x64 tiles (256 blocks = 1/CU) + dbuf
// counted-vmcnt K-loop + T2 swizzle. UNCHANGED from R2.
// ---------------------------------------------------------------------------
__global__ __launch_bounds__(256) void gemm_out(
    const f16* __restrict__ A0, const f16* __restrict__ BT,
    float* __restrict__ outp) {
  const int id = blockIdx.x;
  const int mt = id >> 4, nt = id & 15;
  const f16* Abase = A0 + (size_t)mt * 128 * DIMD;
  const f16* Bbase = BT + (size_t)nt * 64 * DIMD;
  __shared__ alignas(16) f16 As[2][128 * 32];
  __shared__ alignas(16) f16 Bs[2][64 * 32];
  const int tid = threadIdx.x;
  const int wave = tid >> 6, lane = tid & 63;
  const int wm = (wave & 1) * 64, wn = (wave >> 1) * 32;
  const int lrow = lane >> 2;
  const int r16 = lane & 15, q4 = (lane >> 4) * 4;
  const int lcol_sw = (((lane & 3) ^ ((lrow >> 1) & 3)) * 8);
  const int g8sw = (((lane >> 4) ^ ((r16 >> 1) & 3)) * 8);
  f32x4_t acc[4][2] = {};

  auto stage = [&](int k0, int buf) {
    g2l16(Abase + (size_t)(wave * 16 + lrow) * DIMD + k0 + lcol_sw, &As[buf][(wave * 16) * 32]);
    g2l16(Abase + (size_t)(64 + wave * 16 + lrow) * DIMD + k0 + lcol_sw, &As[buf][(64 + wave * 16) * 32]);
    g2l16(Bbase + (size_t)(wave * 16 + lrow) * DIMD + k0 + lcol_sw, &Bs[buf][(wave * 16) * 32]);
  };
  auto body = [&](int kt, int cur) {
    if (kt < 31) asm volatile("s_waitcnt vmcnt(3)" ::: "memory");
    else         asm volatile("s_waitcnt vmcnt(0)" ::: "memory");
    asm volatile("s_barrier" ::: "memory");
    f16x8_t a[4], bf[2];
#pragma unroll
    for (int i = 0; i < 4; i++)
      a[i] = *(const f16x8_t*)&As[cur][(wm + i * 16 + r16) * 32 + g8sw];
#pragma unroll
    for (int j = 0; j < 2; j++)
      bf[j] = *(const f16x8_t*)&Bs[cur][(wn + j * 16 + r16) * 32 + g8sw];
#pragma unroll
    for (int i = 0; i < 4; i++)
#pragma unroll
      for (int j = 0; j < 2; j++)
        acc[i][j] = __builtin_amdgcn_mfma_f32_16x16x32_f16(a[i], bf[j], acc[i][j], 0, 0, 0);
    asm volatile("s_waitcnt lgkmcnt(0)" ::: "memory");
    asm volatile("s_barrier" ::: "memory");
    if (kt + 2 < 32) stage((kt + 2) * 32, cur);
  };
  stage(0, 0);
  stage(32, 1);
#pragma unroll 1
  for (int kt = 0; kt < 32; kt += 2) { body(kt, 0); body(kt + 1, 1); }

  const int m0 = mt * 128, n0 = nt * 64;
#pragma unroll
  for (int i = 0; i < 4; i++) {
#pragma unroll
    for (int j = 0; j < 2; j++) {
      const int col = n0 + wn + j * 16 + r16;
#pragma unroll
      for (int r = 0; r < 4; r++)
        outp[(size_t)(m0 + wm + i * 16 + q4 + r) * DIMD + col] = acc[i][j][r];
    }
  }
}

// ---------------------------------------------------------------------------
// Kernel 4: flash attention — 512 threads (8 waves), K-tile 64, depth-2 async
// K/V dbuf. R1: pair swizzle, defer-max, setprio. R2: T2 swizzle. UNCHANGED.
// ---------------------------------------------------------------------------
__global__ __launch_bounds__(512, 2) void attn_kernel(
    const f16* __restrict__ qbuf, const f16* __restrict__ kbuf,
    const f16* __restrict__ vbuf, f16* __restrict__ attn_out) {
  const int bh = blockIdx.x & 127;   // pair swizzle: bid, bid+128 -> same XCD
  const int qt = blockIdx.x >> 7;
  const int b = bh >> 4, h = bh & 15;
  const f16* qg = qbuf + ((size_t)bh * N2 + qt * 128) * DH;
  const f16* kg = kbuf + (size_t)bh * LTOT * DH;
  const f16* vg = vbuf + (size_t)bh * DH * LTOT;

  __shared__ alignas(16) f16 Ks[2][4096];
  __shared__ alignas(16) f16 Vs[2][4096];
  __shared__ alignas(16) f16 QP[9216];

  const int tid = threadIdx.x, wave = tid >> 6, lane = tid & 63;
  const int lrow = lane >> 2;
  const int r16 = lane & 15, g8 = (lane >> 4) * 8, q4 = (lane >> 4) * 4;
  const int lcol_sw = (((lane & 3) ^ ((lrow >> 1) & 3)) * 8);
  const int g8sw = (((lane >> 4) ^ ((r16 >> 1) & 3)) * 8);
  f16* Ps = &QP[wave * 1152];

#pragma unroll
  for (int i = 0; i < 2; i++) {
    const int c = wave * 2 + i, s = c >> 3, rb = (c & 7) * 16;
    g2l16(qg + (size_t)(rb + lrow) * DH + s * 32 + lcol_sw, &QP[s * 4096 + rb * 32]);
  }
  auto stage = [&](int kt, int buf) {
    const int s = wave >> 2, rb = (wave & 3) * 16;
    g2l16(kg + (size_t)(kt * ATILE + rb + lrow) * DH + s * 32 + lcol_sw,
          &Ks[buf][s * 2048 + rb * 32]);
    g2l16(vg + (size_t)(rb + lrow) * LTOT + kt * ATILE + s * 32 + lcol_sw,
          &Vs[buf][s * 2048 + rb * 32]);
  };
  stage(0, 0);
  stage(1, 1);
  asm volatile("s_waitcnt vmcnt(4)" ::: "memory");
  asm volatile("s_barrier" ::: "memory");
  f16x8_t bQ[2];
#pragma unroll
  for (int s = 0; s < 2; s++)
    bQ[s] = *(const f16x8_t*)&QP[s * 4096 + (wave * 16 + r16) * 32 + g8sw];
  asm volatile("s_waitcnt lgkmcnt(0)" ::: "memory");

  f32x4_t oacc[4] = {};
  float mrow = -1e30f, lsum = 0.0f;
  const float SCL = 0.125f * 1.44269504089f;

  for (int kt = 0; kt < AITERS; kt++) {
    const int cur = kt & 1;
    asm volatile("s_waitcnt vmcnt(2)" ::: "memory");
    asm volatile("s_barrier" ::: "memory");
    f32x4_t sacc[4] = {};
    __builtin_amdgcn_s_setprio(1);
#pragma unroll
    for (int s = 0; s < 2; s++) {
      f16x8_t aK[4];
#pragma unroll
      for (int i = 0; i < 4; i++)
        aK[i] = *(const f16x8_t*)&Ks[cur][s * 2048 + (i * 16 + r16) * 32 + g8sw];
#pragma unroll
      for (int i = 0; i < 4; i++)
        sacc[i] = __builtin_amdgcn_mfma_f32_16x16x32_f16(aK[i], bQ[s], sacc[i], 0, 0, 0);
    }
    __builtin_amdgcn_s_setprio(0);
    float vmax = -1e30f;
#pragma unroll
    for (int i = 0; i < 4; i++)
#pragma unroll
      for (int r = 0; r < 4; r++) vmax = fmaxf(vmax, sacc[i][r]);
    vmax = fmaxf(vmax, __shfl_xor(vmax, 16, 64));
    vmax = fmaxf(vmax, __shfl_xor(vmax, 32, 64));
    const float pm = SCL * vmax;
    if (!__all(pm <= mrow + 8.0f)) {
      const float m_new = fmaxf(mrow, pm);
      const float alpha = exp2f(mrow - m_new);
      lsum *= alpha;
#pragma unroll
      for (int id = 0; id < 4; id++) oacc[id] *= alpha;
      mrow = m_new;
    }
    float psum = 0.0f;
#pragma unroll
    for (int i = 0; i < 4; i++) {
      f16x4_t pk;
#pragma unroll
      for (int r = 0; r < 4; r++) {
        const float p = exp2f(SCL * sacc[i][r] - mrow);
        psum += p;
        pk[r] = (f16)p;
      }
      *(f16x4_t*)&Ps[r16 * 72 + i * 16 + q4] = pk;
    }
    psum += __shfl_xor(psum, 16, 64);
    psum += __shfl_xor(psum, 32, 64);
    lsum += psum;
    __builtin_amdgcn_s_setprio(1);
#pragma unroll
    for (int s2 = 0; s2 < 2; s2++) {
      f16x8_t aV[4];
#pragma unroll
      for (int id = 0; id < 4; id++)
        aV[id] = *(const f16x8_t*)&Vs[cur][s2 * 2048 + (id * 16 + r16) * 32 + g8sw];
      const f16x8_t bP = *(const f16x8_t*)&Ps[r16 * 72 + s2 * 32 + g8];
#pragma unroll
      for (int id = 0; id < 4; id++)
        oacc[id] = __builtin_amdgcn_mfma_f32_16x16x32_f16(aV[id], bP, oacc[id], 0, 0, 0);
    }
    __builtin_amdgcn_s_setprio(0);
    asm volatile("s_waitcnt lgkmcnt(0)" ::: "memory");
    asm volatile("s_barrier" ::: "memory");
    if (kt + 2 < AITERS) stage(kt + 2, cur);
  }
  const float inv = 1.0f / lsum;
  const int q = qt * 128 + wave * 16 + r16;
  const size_t rowbase = ((size_t)(b * N2 + q)) * DIMD + h * DH;
#pragma unroll
  for (int id = 0; id < 4; id++) {
    f16x4_t pk;
#pragma unroll
    for (int r = 0; r < 4; r++) pk[r] = (f16)(oacc[id][r] * inv);
    *(f16x4_t*)&attn_out[rowbase + id * 16 + q4] = pk;
  }
}

// ---------------------------------------------------------------------------
extern "C" void kernel_launch(void* const* d_in, const int* in_sizes, int n_in,
                              void* d_out, int out_size, void* d_ws, size_t ws_size,
                              hipStream_t stream) {
  const float* x     = (const float*)d_in[0];
  const float* lat   = (const float*)d_in[1];
  const float* shift = (const float*)d_in[2];
  const float* scale = (const float*)d_in[3];
  const float* ln1w  = (const float*)d_in[4];
  const float* ln1b  = (const float*)d_in[5];
  const float* ln2w  = (const float*)d_in[6];
  const float* ln2b  = (const float*)d_in[7];
  const float* Wq    = (const float*)d_in[8];
  const float* Wkv   = (const float*)d_in[9];
  const float* Wo    = (const float*)d_in[10];
  float* outp = (float*)d_out;

  char* ws = (char*)d_ws;
  f16* kv_in = (f16*)ws;                 ws += (size_t)MKV * DIMD * 2;          // 68 MB
  f16* Wq16  = (f16*)ws;                 ws += (size_t)1024 * 1024 * 2;         // 2 MB
  f16* Wkv16 = (f16*)ws;                 ws += (size_t)2048 * 1024 * 2;         // 4 MB
  f16* Wo16  = (f16*)ws;                 ws += (size_t)1024 * 1024 * 2;         // 2 MB
  f16* qbuf  = (f16*)ws;                 ws += (size_t)B_SZ * HEADS * N2 * DH * 2;   // 4 MB
  f16* kbuf  = (f16*)ws;                 ws += (size_t)B_SZ * HEADS * LTOT * DH * 2; // 68 MB
  f16* vbuf  = (f16*)ws;                 ws += (size_t)B_SZ * HEADS * LTOT * DH * 2; // 68 MB
  f16* aout  = (f16*)ws;                 ws += (size_t)B_SZ * N2 * DIMD * 2;         // 4 MB

  prep_kernel<<<dim3(MKV + 4096), dim3(256), 0, stream>>>(
      x, lat, shift, scale, ln1w, ln1b, ln2w, ln2b, Wq, Wkv, Wo,
      kv_in, Wq16, Wkv16, Wo16);
  gemm_pre<<<dim3(G0B + 32), dim3(512), 0, stream>>>(
      kv_in, Wkv16, Wq16, kbuf, vbuf, qbuf);
  attn_kernel<<<dim3(256), dim3(512), 0, stream>>>(qbuf, kbuf, vbuf, aout);
  gemm_out<<<dim3(256), dim3(256), 0, stream>>>(aout, Wo16, outp);
}

// Round 5
// 518.950 us; speedup vs baseline: 1.0140x; 1.0092x over previous
//
#include <hip/hip_runtime.h>
#include <cstdint>
#include <cstddef>

#define B_SZ 8
#define N1 4096
#define N2 256
#define LTOT 4352          // N1 + N2
#define DIMD 1024
#define HEADS 16
#define DH 64
#define MKV (B_SZ * LTOT)  // 34816
#define ATILE 64
#define AITERS (LTOT / ATILE)  // 68
#define G0B 1088               // KV blocks: 136 mt x 8 nt (256x256 tiles)

typedef _Float16 f16;
typedef f16 f16x4_t __attribute__((ext_vector_type(4)));
typedef f16 f16x8_t __attribute__((ext_vector_type(8)));
typedef float f32x4_t __attribute__((ext_vector_type(4)));

// async global -> LDS, 16B per lane. LDS dest is wave-uniform base + lane*16.
__device__ __forceinline__ void g2l16(const void* g, void* l) {
  __builtin_amdgcn_global_load_lds(
      (__attribute__((address_space(1))) void*)g,
      (__attribute__((address_space(3))) void*)l, 16, 0, 0);
}

// ---------------------------------------------------------------------------
// Kernel 1: prep = layernorm/modulation (blocks 0..MKV-1) + weight casts
// ---------------------------------------------------------------------------
__global__ __launch_bounds__(256) void prep_kernel(
    const float* __restrict__ x, const float* __restrict__ lat,
    const float* __restrict__ shift, const float* __restrict__ scale,
    const float* __restrict__ ln1w, const float* __restrict__ ln1b,
    const float* __restrict__ ln2w, const float* __restrict__ ln2b,
    const float* __restrict__ Wq, const float* __restrict__ Wkv,
    const float* __restrict__ Wo, f16* __restrict__ kv_in,
    f16* __restrict__ Wq16, f16* __restrict__ Wkv16, f16* __restrict__ Wo16) {
  const int bid = blockIdx.x;
  const int tid = threadIdx.x;
  if (bid >= MKV) {  // weight casts: 1024 f32 per block
    const int c = bid - MKV;
    const float* src;
    f16* dst;
    int off;
    if (c < 1024) { src = Wq; dst = Wq16; off = c; }
    else if (c < 3072) { src = Wkv; dst = Wkv16; off = c - 1024; }
    else { src = Wo; dst = Wo16; off = c - 3072; }
    const int i = off * 256 + tid;
    float4 v = ((const float4*)src)[i];
    f16x4_t o = {(f16)v.x, (f16)v.y, (f16)v.z, (f16)v.w};
    ((f16x4_t*)dst)[i] = o;
    return;
  }
  const int row = bid;
  const int b = row / LTOT;
  const int n = row - b * LTOT;
  const bool is_lat = (n >= N1);
  const float* src = is_lat ? (lat + (size_t)(b * N2 + (n - N1)) * DIMD)
                            : (x + (size_t)(b * N1 + n) * DIMD);
  float4 v = ((const float4*)src)[tid];
  float s = v.x + v.y + v.z + v.w;
  float s2 = v.x * v.x + v.y * v.y + v.z * v.z + v.w * v.w;
#pragma unroll
  for (int m = 1; m <= 32; m <<= 1) {
    s += __shfl_xor(s, m, 64);
    s2 += __shfl_xor(s2, m, 64);
  }
  __shared__ float red[8];
  const int wave = tid >> 6;
  if ((tid & 63) == 0) { red[wave * 2] = s; red[wave * 2 + 1] = s2; }
  __syncthreads();
  s = red[0] + red[2] + red[4] + red[6];
  s2 = red[1] + red[3] + red[5] + red[7];
  const float mean = s * (1.0f / DIMD);
  const float var = fmaxf(s2 * (1.0f / DIMD) - mean * mean, 0.0f);
  const float rstd = rsqrtf(var + 1e-5f);
  const float4 w4 = ((const float4*)(is_lat ? ln2w : ln1w))[tid];
  const float4 b4 = ((const float4*)(is_lat ? ln2b : ln1b))[tid];
  float y0 = (v.x - mean) * rstd * w4.x + b4.x;
  float y1 = (v.y - mean) * rstd * w4.y + b4.y;
  float y2 = (v.z - mean) * rstd * w4.z + b4.z;
  float y3 = (v.w - mean) * rstd * w4.w + b4.w;
  if (is_lat) {
    float4 sc = ((const float4*)(scale + (size_t)b * DIMD))[tid];
    float4 sh = ((const float4*)(shift + (size_t)b * DIMD))[tid];
    y0 = y0 * (1.0f + sc.x) + sh.x;
    y1 = y1 * (1.0f + sc.y) + sh.y;
    y2 = y2 * (1.0f + sc.z) + sh.z;
    y3 = y3 * (1.0f + sc.w) + sh.w;
  }
  f16x4_t o = {(f16)y0, (f16)y1, (f16)y2, (f16)y3};
  *(f16x4_t*)(kv_in + (size_t)row * DIMD + tid * 4) = o;
}

// ---------------------------------------------------------------------------
// Kernel 2: fused pre-attention GEMMs (kv + q), 8-phase 256x256 template.
// R5: ONE barrier per phase (was 2). Waves may slide <=1 phase (bounded by
// the remaining barrier); one wave's ds_read service + stage issue overlap
// another wave's MFMA cluster. Hazard ledger: every stage target's last
// reader drained (LGKM0) >=2 phases / >=1 barrier earlier under max skew 1:
//   stA(kA,1,1)@W0: buf1.A1 read p6-prev, drained pre-BARR(p7)   OK
//   stB(kA,1,0)@W1: buf1.B0 read p4,      drained pre-BARR(p4)   OK
//   stA(kB,0,0)@W2: buf0.A0 read p0,      drained pre-BARR(p1)   OK
//   stB(kB,0,1)@W3: buf0.B1 read p1,      drained pre-BARR(p2)   OK
//   stA(kB,0,1)@W4: buf0.A1 read p2,      drained pre-BARR(p3)   OK
//   stB(kB,0,0)@W5: buf0.B0 read p0,      drained pre-BARR(p1)   OK
//   stA(kC,1,0)@W6: buf1.A0 read p4,      drained pre-BARR(p5)   OK
//   stB(kC,1,1)@W7: buf1.B1 read p5,      drained pre-BARR(p6)   OK
// VM4 (per-wave) before BARR(p3)/BARR(p7) publishes the opposite buffer for
// the following 4 phases (unchanged vmcnt accounting). R5 also hoists stage
// addressing: swizzled source col (c8^(t8&7))*8 is j-invariant -> per-thread
// 64-bit base precomputed once; per-call address = base + const + kt*64.
// ---------------------------------------------------------------------------
#define DS_A(buf, mh)                                                          \
  _Pragma("unroll") for (int i_ = 0; i_ < 4; i_++)                             \
  _Pragma("unroll") for (int ks_ = 0; ks_ < 2; ks_++)                          \
      aF[i_][ks_] = *(const f16x8_t*)&As[buf][mh][                             \
          (wrow * 64 + i_ * 16 + r16) * 64 + (((ks_ * 4 + g8i) ^ xk) * 8)];

#define DS_B(dst, buf, nh)                                                     \
  _Pragma("unroll") for (int j_ = 0; j_ < 2; j_++)                             \
  _Pragma("unroll") for (int ks_ = 0; ks_ < 2; ks_++)                          \
      dst[j_][ks_] = *(const f16x8_t*)&Bs[buf][nh][                            \
          (wcol * 32 + j_ * 16 + r16) * 64 + (((ks_ * 4 + g8i) ^ xk) * 8)];

#define MFMA16(mh, nh, BF)                                                     \
  __builtin_amdgcn_s_setprio(1);                                               \
  _Pragma("unroll") for (int ks_ = 0; ks_ < 2; ks_++)                          \
  _Pragma("unroll") for (int i_ = 0; i_ < 4; i_++)                             \
  _Pragma("unroll") for (int j_ = 0; j_ < 2; j_++)                             \
      acc[(mh)*4 + i_][(nh)*2 + j_] = __builtin_amdgcn_mfma_f32_16x16x32_f16(  \
          aF[i_][ks_], BF[j_][ks_], acc[(mh)*4 + i_][(nh)*2 + j_], 0, 0, 0);   \
  __builtin_amdgcn_s_setprio(0);

#define BARR asm volatile("s_barrier" ::: "memory")
#define LGKM0 asm volatile("s_waitcnt lgkmcnt(0)" ::: "memory")
#define VM4 asm volatile("s_waitcnt vmcnt(4)" ::: "memory")

__global__ __launch_bounds__(512, 2) void gemm_pre(
    const f16* __restrict__ kv_in, const f16* __restrict__ Wkv16,
    const f16* __restrict__ Wq16, f16* __restrict__ kbuf,
    f16* __restrict__ vbuf, f16* __restrict__ qbuf) {
  const int id = blockIdx.x;
  const bool is_kv = (id < G0B);
  int mt = 0, nt;
  const f16 *Abase, *Bbase;
  if (is_kv) {
    const int xcd = id & 7, l = id >> 3;   // 1088 = 8 * 136, bijective
    mt = xcd * 17 + (l >> 3);              // 136 mt, 17 per XCD
    nt = l & 7;
    Abase = kv_in + (size_t)mt * 256 * DIMD;
    Bbase = Wkv16 + (size_t)nt * 256 * DIMD;
  } else {
    const int id2 = id - G0B;
    const int bq = id2 >> 2;               // batch 0..7
    nt = id2 & 3;
    Abase = kv_in + ((size_t)(bq * LTOT + N1)) * DIMD;
    Bbase = Wq16 + (size_t)nt * 256 * DIMD;
  }
  __shared__ alignas(16) f16 As[2][2][128 * 64];
  __shared__ alignas(16) f16 Bs[2][2][128 * 64];
  const int tid = threadIdx.x;
  const int wave = tid >> 6, lane = tid & 63;
  const int wrow = wave >> 2, wcol = wave & 3;
  const int r16 = lane & 15, g8i = lane >> 4, q4 = (lane >> 4) * 4;
  const int xk = r16 & 7;
  const int t8 = tid >> 3, c8 = tid & 7;
  f32x4_t acc[8][4] = {};
  f16x8_t aF[4][2], b0F[2][2], b1F[2][2];

  // hoisted per-thread source bases (swizzled col is j-invariant: t8&7)
  const int col8 = (c8 ^ (t8 & 7)) * 8;
  const f16* Asrc = Abase + (size_t)t8 * DIMD + col8;
  const f16* Bsrc = Bbase + (size_t)((t8 >> 5) * 64 + (t8 & 31)) * DIMD + col8;

  auto stageA = [&](int kt, int buf, int mh) {
#pragma unroll
    for (int j = 0; j < 2; j++)
      g2l16(Asrc + (size_t)(j * 128 + mh * 64) * DIMD + kt * 64,
            &As[buf][mh][(j * 512 + wave * 64) * 8]);
  };
  auto stageB = [&](int kt, int buf, int nh) {
#pragma unroll
    for (int j = 0; j < 2; j++)
      g2l16(Bsrc + (size_t)(j * 128 + nh * 32) * DIMD + kt * 64,
            &Bs[buf][nh][(j * 512 + wave * 64) * 8]);
  };

  // prologue: K0 all 4 halves + K1 {A0, B1}; vmcnt(4) => K0 landed
  stageA(0, 0, 0); stageB(0, 0, 1); stageA(0, 0, 1); stageB(0, 0, 0);
  stageA(1, 1, 0); stageB(1, 1, 1);
  VM4; BARR;

#pragma unroll 1
  for (int it = 0; it < 8; ++it) {
    const int kA = 2 * it + 1;
    const int kB = (2 * it + 2 > 15) ? 15 : 2 * it + 2;  // clamp: dead-staged
    const int kC = (2 * it + 3 > 15) ? 15 : 2 * it + 3;
    // p0: quadrant (0,0) of buf0
    DS_A(0, 0); DS_B(b0F, 0, 0);
    stageA(kA, 1, 1);
    BARR; LGKM0; MFMA16(0, 0, b0F);
    // p1: (0,1)
    DS_B(b1F, 0, 1);
    stageB(kA, 1, 0);
    BARR; LGKM0; MFMA16(0, 1, b1F);
    // p2: (1,1)
    DS_A(0, 1);
    stageA(kB, 0, 0);
    BARR; LGKM0; MFMA16(1, 1, b1F);
    // p3: (1,0); vmcnt(4) publishes buf1 (K 2i+1) for p4-7
    stageB(kB, 0, 1);
    VM4;
    BARR; LGKM0; MFMA16(1, 0, b0F);
    // p4: (0,0) of buf1
    DS_A(1, 0); DS_B(b0F, 1, 0);
    stageA(kB, 0, 1);
    BARR; LGKM0; MFMA16(0, 0, b0F);
    // p5: (0,1)
    DS_B(b1F, 1, 1);
    stageB(kB, 0, 0);
    BARR; LGKM0; MFMA16(0, 1, b1F);
    // p6: (1,1)
    DS_A(1, 1);
    stageA(kC, 1, 0);
    BARR; LGKM0; MFMA16(1, 1, b1F);
    // p7: (1,0); vmcnt(4) publishes buf0 (K 2i+2) for next iter p0-3
    stageB(kC, 1, 1);
    VM4;
    BARR; LGKM0; MFMA16(1, 0, b0F);
  }
  asm volatile("s_waitcnt vmcnt(0)" ::: "memory");  // drain dead stages

  if (is_kv) {
    const int m0 = mt * 256;
    const int b = m0 / LTOT;
    const int n0 = m0 - b * LTOT;
    if (nt < 4) {  // k half: ((b*16+h)*4352 + n)*64 + d
#pragma unroll
      for (int ai = 0; ai < 8; ai++) {
        const int n_base = n0 + wrow * 128 + (ai >> 2) * 64 + (ai & 3) * 16 + q4;
#pragma unroll
        for (int bj = 0; bj < 4; bj++) {
          const int e = nt * 256 + wcol * 64 + (bj >> 1) * 32 + (bj & 1) * 16 + r16;
          const int h = e >> 6, d = e & 63;
          const size_t base = (size_t)(b * HEADS + h) * LTOT;
#pragma unroll
          for (int r = 0; r < 4; r++)
            kbuf[(base + n_base + r) * DH + d] = (f16)acc[ai][bj][r];
        }
      }
    } else {  // v half, transposed: ((b*16+h)*64 + d)*4352 + n
#pragma unroll
      for (int ai = 0; ai < 8; ai++) {
        const int n_base = n0 + wrow * 128 + (ai >> 2) * 64 + (ai & 3) * 16 + q4;
#pragma unroll
        for (int bj = 0; bj < 4; bj++) {
          const int e = (nt - 4) * 256 + wcol * 64 + (bj >> 1) * 32 + (bj & 1) * 16 + r16;
          const int h = e >> 6, d = e & 63;
          f16x4_t pk = {(f16)acc[ai][bj][0], (f16)acc[ai][bj][1],
                        (f16)acc[ai][bj][2], (f16)acc[ai][bj][3]};
          *(f16x4_t*)&vbuf[((size_t)(b * HEADS + h) * DH + d) * LTOT + n_base] = pk;
        }
      }
    }
  } else {  // q: ((b*16+h)*256 + n)*64 + d
    const int b = (id - G0B) >> 2;
#pragma unroll
    for (int ai = 0; ai < 8; ai++) {
      const int qn = wrow * 128 + (ai >> 2) * 64 + (ai & 3) * 16 + q4;
#pragma unroll
      for (int bj = 0; bj < 4; bj++) {
        const int e = nt * 256 + wcol * 64 + (bj >> 1) * 32 + (bj & 1) * 16 + r16;
        const int h = e >> 6, d = e & 63;
#pragma unroll
        for (int r = 0; r < 4; r++)
          qbuf[((size_t)(b * HEADS + h) * N2 + qn + r) * DH + d] = (f16)acc[ai][bj][r];
      }
    }
  }
}

// ---------------------------------------------------------------------------
// Kernel 3: out GEMM -> f32 d_out. 128x64 tiles (256 blocks = 1/CU) + dbuf
// counted-vmcnt K-loop + T2 swizzle. UNCHANGED.
// ---------------------------------------------------------------------------
__global__ __launch_bounds__(256) void gemm_out(
    const f16* __restrict__ A0, const f16* __restrict__ BT,
    float* __restrict__ outp) {
  const int id = blockIdx.x;
  const int mt = id >> 4, nt = id & 15;
  const f16* Abase = A0 + (size_t)mt * 128 * DIMD;
  const f16* Bbase = BT + (size_t)nt * 64 * DIMD;
  __shared__ alignas(16) f16 As[2][128 * 32];
  __shared__ alignas(16) f16 Bs[2][64 * 32];
  const int tid = threadIdx.x;
  const int wave = tid >> 6, lane = tid & 63;
  const int wm = (wave & 1) * 64, wn = (wave >> 1) * 32;
  const int lrow = lane >> 2;
  const int r16 = lane & 15, q4 = (lane >> 4) * 4;
  const int lcol_sw = (((lane & 3) ^ ((lrow >> 1) & 3)) * 8);
  const int g8sw = (((lane >> 4) ^ ((r16 >> 1) & 3)) * 8);
  f32x4_t acc[4][2] = {};

  auto stage = [&](int k0, int buf) {
    g2l16(Abase + (size_t)(wave * 16 + lrow) * DIMD + k0 + lcol_sw, &As[buf][(wave * 16) * 32]);
    g2l16(Abase + (size_t)(64 + wave * 16 + lrow) * DIMD + k0 + lcol_sw, &As[buf][(64 + wave * 16) * 32]);
    g2l16(Bbase + (size_t)(wave * 16 + lrow) * DIMD + k0 + lcol_sw, &Bs[buf][(wave * 16) * 32]);
  };
  auto body = [&](int kt, int cur) {
    if (kt < 31) asm volatile("s_waitcnt vmcnt(3)" ::: "memory");
    else         asm volatile("s_waitcnt vmcnt(0)" ::: "memory");
    asm volatile("s_barrier" ::: "memory");
    f16x8_t a[4], bf[2];
#pragma unroll
    for (int i = 0; i < 4; i++)
      a[i] = *(const f16x8_t*)&As[cur][(wm + i * 16 + r16) * 32 + g8sw];
#pragma unroll
    for (int j = 0; j < 2; j++)
      bf[j] = *(const f16x8_t*)&Bs[cur][(wn + j * 16 + r16) * 32 + g8sw];
#pragma unroll
    for (int i = 0; i < 4; i++)
#pragma unroll
      for (int j = 0; j < 2; j++)
        acc[i][j] = __builtin_amdgcn_mfma_f32_16x16x32_f16(a[i], bf[j], acc[i][j], 0, 0, 0);
    asm volatile("s_waitcnt lgkmcnt(0)" ::: "memory");
    asm volatile("s_barrier" ::: "memory");
    if (kt + 2 < 32) stage((kt + 2) * 32, cur);
  };
  stage(0, 0);
  stage(32, 1);
#pragma unroll 1
  for (int kt = 0; kt < 32; kt += 2) { body(kt, 0); body(kt + 1, 1); }

  const int m0 = mt * 128, n0 = nt * 64;
#pragma unroll
  for (int i = 0; i < 4; i++) {
#pragma unroll
    for (int j = 0; j < 2; j++) {
      const int col = n0 + wn + j * 16 + r16;
#pragma unroll
      for (int r = 0; r < 4; r++)
        outp[(size_t)(m0 + wm + i * 16 + q4 + r) * DIMD + col] = acc[i][j][r];
    }
  }
}

// ---------------------------------------------------------------------------
// Kernel 4: flash attention — 512 threads (8 waves), K-tile 64, depth-2 async
// K/V dbuf. R1: pair swizzle, defer-max, setprio. R2: T2 swizzle. UNCHANGED.
// ---------------------------------------------------------------------------
__global__ __launch_bounds__(512, 2) void attn_kernel(
    const f16* __restrict__ qbuf, const f16* __restrict__ kbuf,
    const f16* __restrict__ vbuf, f16* __restrict__ attn_out) {
  const int bh = blockIdx.x & 127;   // pair swizzle: bid, bid+128 -> same XCD
  const int qt = blockIdx.x >> 7;
  const int b = bh >> 4, h = bh & 15;
  const f16* qg = qbuf + ((size_t)bh * N2 + qt * 128) * DH;
  const f16* kg = kbuf + (size_t)bh * LTOT * DH;
  const f16* vg = vbuf + (size_t)bh * DH * LTOT;

  __shared__ alignas(16) f16 Ks[2][4096];
  __shared__ alignas(16) f16 Vs[2][4096];
  __shared__ alignas(16) f16 QP[9216];

  const int tid = threadIdx.x, wave = tid >> 6, lane = tid & 63;
  const int lrow = lane >> 2;
  const int r16 = lane & 15, g8 = (lane >> 4) * 8, q4 = (lane >> 4) * 4;
  const int lcol_sw = (((lane & 3) ^ ((lrow >> 1) & 3)) * 8);
  const int g8sw = (((lane >> 4) ^ ((r16 >> 1) & 3)) * 8);
  f16* Ps = &QP[wave * 1152];

#pragma unroll
  for (int i = 0; i < 2; i++) {
    const int c = wave * 2 + i, s = c >> 3, rb = (c & 7) * 16;
    g2l16(qg + (size_t)(rb + lrow) * DH + s * 32 + lcol_sw, &QP[s * 4096 + rb * 32]);
  }
  auto stage = [&](int kt, int buf) {
    const int s = wave >> 2, rb = (wave & 3) * 16;
    g2l16(kg + (size_t)(kt * ATILE + rb + lrow) * DH + s * 32 + lcol_sw,
          &Ks[buf][s * 2048 + rb * 32]);
    g2l16(vg + (size_t)(rb + lrow) * LTOT + kt * ATILE + s * 32 + lcol_sw,
          &Vs[buf][s * 2048 + rb * 32]);
  };
  stage(0, 0);
  stage(1, 1);
  asm volatile("s_waitcnt vmcnt(4)" ::: "memory");
  asm volatile("s_barrier" ::: "memory");
  f16x8_t bQ[2];
#pragma unroll
  for (int s = 0; s < 2; s++)
    bQ[s] = *(const f16x8_t*)&QP[s * 4096 + (wave * 16 + r16) * 32 + g8sw];
  asm volatile("s_waitcnt lgkmcnt(0)" ::: "memory");

  f32x4_t oacc[4] = {};
  float mrow = -1e30f, lsum = 0.0f;
  const float SCL = 0.125f * 1.44269504089f;

  for (int kt = 0; kt < AITERS; kt++) {
    const int cur = kt & 1;
    asm volatile("s_waitcnt vmcnt(2)" ::: "memory");
    asm volatile("s_barrier" ::: "memory");
    f32x4_t sacc[4] = {};
    __builtin_amdgcn_s_setprio(1);
#pragma unroll
    for (int s = 0; s < 2; s++) {
      f16x8_t aK[4];
#pragma unroll
      for (int i = 0; i < 4; i++)
        aK[i] = *(const f16x8_t*)&Ks[cur][s * 2048 + (i * 16 + r16) * 32 + g8sw];
#pragma unroll
      for (int i = 0; i < 4; i++)
        sacc[i] = __builtin_amdgcn_mfma_f32_16x16x32_f16(aK[i], bQ[s], sacc[i], 0, 0, 0);
    }
    __builtin_amdgcn_s_setprio(0);
    float vmax = -1e30f;
#pragma unroll
    for (int i = 0; i < 4; i++)
#pragma unroll
      for (int r = 0; r < 4; r++) vmax = fmaxf(vmax, sacc[i][r]);
    vmax = fmaxf(vmax, __shfl_xor(vmax, 16, 64));
    vmax = fmaxf(vmax, __shfl_xor(vmax, 32, 64));
    const float pm = SCL * vmax;
    if (!__all(pm <= mrow + 8.0f)) {
      const float m_new = fmaxf(mrow, pm);
      const float alpha = exp2f(mrow - m_new);
      lsum *= alpha;
#pragma unroll
      for (int id = 0; id < 4; id++) oacc[id] *= alpha;
      mrow = m_new;
    }
    float psum = 0.0f;
#pragma unroll
    for (int i = 0; i < 4; i++) {
      f16x4_t pk;
#pragma unroll
      for (int r = 0; r < 4; r++) {
        const float p = exp2f(SCL * sacc[i][r] - mrow);
        psum += p;
        pk[r] = (f16)p;
      }
      *(f16x4_t*)&Ps[r16 * 72 + i * 16 + q4] = pk;
    }
    psum += __shfl_xor(psum, 16, 64);
    psum += __shfl_xor(psum, 32, 64);
    lsum += psum;
    __builtin_amdgcn_s_setprio(1);
#pragma unroll
    for (int s2 = 0; s2 < 2; s2++) {
      f16x8_t aV[4];
#pragma unroll
      for (int id = 0; id < 4; id++)
        aV[id] = *(const f16x8_t*)&Vs[cur][s2 * 2048 + (id * 16 + r16) * 32 + g8sw];
      const f16x8_t bP = *(const f16x8_t*)&Ps[r16 * 72 + s2 * 32 + g8];
#pragma unroll
      for (int id = 0; id < 4; id++)
        oacc[id] = __builtin_amdgcn_mfma_f32_16x16x32_f16(aV[id], bP, oacc[id], 0, 0, 0);
    }
    __builtin_amdgcn_s_setprio(0);
    asm volatile("s_waitcnt lgkmcnt(0)" ::: "memory");
    asm volatile("s_barrier" ::: "memory");
    if (kt + 2 < AITERS) stage(kt + 2, cur);
  }
  const float inv = 1.0f / lsum;
  const int q = qt * 128 + wave * 16 + r16;
  const size_t rowbase = ((size_t)(b * N2 + q)) * DIMD + h * DH;
#pragma unroll
  for (int id = 0; id < 4; id++) {
    f16x4_t pk;
#pragma unroll
    for (int r = 0; r < 4; r++) pk[r] = (f16)(oacc[id][r] * inv);
    *(f16x4_t*)&attn_out[rowbase + id * 16 + q4] = pk;
  }
}

// ---------------------------------------------------------------------------
extern "C" void kernel_launch(void* const* d_in, const int* in_sizes, int n_in,
                              void* d_out, int out_size, void* d_ws, size_t ws_size,
                              hipStream_t stream) {
  const float* x     = (const float*)d_in[0];
  const float* lat   = (const float*)d_in[1];
  const float* shift = (const float*)d_in[2];
  const float* scale = (const float*)d_in[3];
  const float* ln1w  = (const float*)d_in[4];
  const float* ln1b  = (const float*)d_in[5];
  const float* ln2w  = (const float*)d_in[6];
  const float* ln2b  = (const float*)d_in[7];
  const float* Wq    = (const float*)d_in[8];
  const float* Wkv   = (const float*)d_in[9];
  const float* Wo    = (const float*)d_in[10];
  float* outp = (float*)d_out;

  char* ws = (char*)d_ws;
  f16* kv_in = (f16*)ws;                 ws += (size_t)MKV * DIMD * 2;          // 68 MB
  f16* Wq16  = (f16*)ws;                 ws += (size_t)1024 * 1024 * 2;         // 2 MB
  f16* Wkv16 = (f16*)ws;                 ws += (size_t)2048 * 1024 * 2;         // 4 MB
  f16* Wo16  = (f16*)ws;                 ws += (size_t)1024 * 1024 * 2;         // 2 MB
  f16* qbuf  = (f16*)ws;                 ws += (size_t)B_SZ * HEADS * N2 * DH * 2;   // 4 MB
  f16* kbuf  = (f16*)ws;                 ws += (size_t)B_SZ * HEADS * LTOT * DH * 2; // 68 MB
  f16* vbuf  = (f16*)ws;                 ws += (size_t)B_SZ * HEADS * LTOT * DH * 2; // 68 MB
  f16* aout  = (f16*)ws;                 ws += (size_t)B_SZ * N2 * DIMD * 2;         // 4 MB

  prep_kernel<<<dim3(MKV + 4096), dim3(256), 0, stream>>>(
      x, lat, shift, scale, ln1w, ln1b, ln2w, ln2b, Wq, Wkv, Wo,
      kv_in, Wq16, Wkv16, Wo16);
  gemm_pre<<<dim3(G0B + 32), dim3(512), 0, stream>>>(
      kv_in, Wkv16, Wq16, kbuf, vbuf, qbuf);
  attn_kernel<<<dim3(256), dim3(512), 0, stream>>>(qbuf, kbuf, vbuf, aout);
  gemm_out<<<dim3(256), dim3(256), 0, stream>>>(aout, Wo16, outp);
}

// Round 6
// 489.910 us; speedup vs baseline: 1.0741x; 1.0593x over previous
//
#include <hip/hip_runtime.h>
#include <cstdint>
#include <cstddef>

#define B_SZ 8
#define N1 4096
#define N2 256
#define LTOT 4352          // N1 + N2
#define DIMD 1024
#define HEADS 16
#define DH 64
#define MKV (B_SZ * LTOT)  // 34816
#define ATILE 64
#define AITERS (LTOT / ATILE)  // 68
#define G0B 1088               // KV blocks: 136 mt x 8 nt (256x256 tiles)

typedef _Float16 f16;
typedef f16 f16x4_t __attribute__((ext_vector_type(4)));
typedef f16 f16x8_t __attribute__((ext_vector_type(8)));
typedef float f32x4_t __attribute__((ext_vector_type(4)));

// async global -> LDS, 16B per lane. LDS dest is wave-uniform base + lane*16.
__device__ __forceinline__ void g2l16(const void* g, void* l) {
  __builtin_amdgcn_global_load_lds(
      (__attribute__((address_space(1))) void*)g,
      (__attribute__((address_space(3))) void*)l, 16, 0, 0);
}

// ---------------------------------------------------------------------------
// Kernel 1: prep = layernorm/modulation (blocks 0..MKV-1) + weight casts
// ---------------------------------------------------------------------------
__global__ __launch_bounds__(256) void prep_kernel(
    const float* __restrict__ x, const float* __restrict__ lat,
    const float* __restrict__ shift, const float* __restrict__ scale,
    const float* __restrict__ ln1w, const float* __restrict__ ln1b,
    const float* __restrict__ ln2w, const float* __restrict__ ln2b,
    const float* __restrict__ Wq, const float* __restrict__ Wkv,
    const float* __restrict__ Wo, f16* __restrict__ kv_in,
    f16* __restrict__ Wq16, f16* __restrict__ Wkv16, f16* __restrict__ Wo16) {
  const int bid = blockIdx.x;
  const int tid = threadIdx.x;
  if (bid >= MKV) {  // weight casts: 1024 f32 per block
    const int c = bid - MKV;
    const float* src;
    f16* dst;
    int off;
    if (c < 1024) { src = Wq; dst = Wq16; off = c; }
    else if (c < 3072) { src = Wkv; dst = Wkv16; off = c - 1024; }
    else { src = Wo; dst = Wo16; off = c - 3072; }
    const int i = off * 256 + tid;
    float4 v = ((const float4*)src)[i];
    f16x4_t o = {(f16)v.x, (f16)v.y, (f16)v.z, (f16)v.w};
    ((f16x4_t*)dst)[i] = o;
    return;
  }
  const int row = bid;
  const int b = row / LTOT;
  const int n = row - b * LTOT;
  const bool is_lat = (n >= N1);
  const float* src = is_lat ? (lat + (size_t)(b * N2 + (n - N1)) * DIMD)
                            : (x + (size_t)(b * N1 + n) * DIMD);
  float4 v = ((const float4*)src)[tid];
  float s = v.x + v.y + v.z + v.w;
  float s2 = v.x * v.x + v.y * v.y + v.z * v.z + v.w * v.w;
#pragma unroll
  for (int m = 1; m <= 32; m <<= 1) {
    s += __shfl_xor(s, m, 64);
    s2 += __shfl_xor(s2, m, 64);
  }
  __shared__ float red[8];
  const int wave = tid >> 6;
  if ((tid & 63) == 0) { red[wave * 2] = s; red[wave * 2 + 1] = s2; }
  __syncthreads();
  s = red[0] + red[2] + red[4] + red[6];
  s2 = red[1] + red[3] + red[5] + red[7];
  const float mean = s * (1.0f / DIMD);
  const float var = fmaxf(s2 * (1.0f / DIMD) - mean * mean, 0.0f);
  const float rstd = rsqrtf(var + 1e-5f);
  const float4 w4 = ((const float4*)(is_lat ? ln2w : ln1w))[tid];
  const float4 b4 = ((const float4*)(is_lat ? ln2b : ln1b))[tid];
  float y0 = (v.x - mean) * rstd * w4.x + b4.x;
  float y1 = (v.y - mean) * rstd * w4.y + b4.y;
  float y2 = (v.z - mean) * rstd * w4.z + b4.z;
  float y3 = (v.w - mean) * rstd * w4.w + b4.w;
  if (is_lat) {
    float4 sc = ((const float4*)(scale + (size_t)b * DIMD))[tid];
    float4 sh = ((const float4*)(shift + (size_t)b * DIMD))[tid];
    y0 = y0 * (1.0f + sc.x) + sh.x;
    y1 = y1 * (1.0f + sc.y) + sh.y;
    y2 = y2 * (1.0f + sc.z) + sh.z;
    y3 = y3 * (1.0f + sc.w) + sh.w;
  }
  f16x4_t o = {(f16)y0, (f16)y1, (f16)y2, (f16)y3};
  *(f16x4_t*)(kv_in + (size_t)row * DIMD + tid * 4) = o;
}

// ---------------------------------------------------------------------------
// Kernel 2: fused pre-attention GEMMs (kv + q), 8-phase 256x256 template.
// R6: removed explicit LGKM0 after each barrier — operands are plain C++
// ds_reads, so hipcc emits per-use fine-grained lgkmcnt(N); early MFMAs start
// under partial drain instead of serializing on a full-queue drain.
// Ledger unchanged: each phase's reads drain before its own MFMA completes,
// which precedes the next BARR, which precedes any re-stage of that buffer
// (all R5 stage->reader distances >=1 barrier, re-verified).
// ---------------------------------------------------------------------------
#define DS_A(buf, mh)                                                          \
  _Pragma("unroll") for (int i_ = 0; i_ < 4; i_++)                             \
  _Pragma("unroll") for (int ks_ = 0; ks_ < 2; ks_++)                          \
      aF[i_][ks_] = *(const f16x8_t*)&As[buf][mh][                             \
          (wrow * 64 + i_ * 16 + r16) * 64 + (((ks_ * 4 + g8i) ^ xk) * 8)];

#define DS_B(dst, buf, nh)                                                     \
  _Pragma("unroll") for (int j_ = 0; j_ < 2; j_++)                             \
  _Pragma("unroll") for (int ks_ = 0; ks_ < 2; ks_++)                          \
      dst[j_][ks_] = *(const f16x8_t*)&Bs[buf][nh][                            \
          (wcol * 32 + j_ * 16 + r16) * 64 + (((ks_ * 4 + g8i) ^ xk) * 8)];

#define MFMA16(mh, nh, BF)                                                     \
  __builtin_amdgcn_s_setprio(1);                                               \
  _Pragma("unroll") for (int ks_ = 0; ks_ < 2; ks_++)                          \
  _Pragma("unroll") for (int i_ = 0; i_ < 4; i_++)                             \
  _Pragma("unroll") for (int j_ = 0; j_ < 2; j_++)                             \
      acc[(mh)*4 + i_][(nh)*2 + j_] = __builtin_amdgcn_mfma_f32_16x16x32_f16(  \
          aF[i_][ks_], BF[j_][ks_], acc[(mh)*4 + i_][(nh)*2 + j_], 0, 0, 0);   \
  __builtin_amdgcn_s_setprio(0);

#define BARR asm volatile("s_barrier" ::: "memory")
#define VM4 asm volatile("s_waitcnt vmcnt(4)" ::: "memory")

__global__ __launch_bounds__(512, 2) void gemm_pre(
    const f16* __restrict__ kv_in, const f16* __restrict__ Wkv16,
    const f16* __restrict__ Wq16, f16* __restrict__ kbuf,
    f16* __restrict__ vbuf, f16* __restrict__ qbuf) {
  const int id = blockIdx.x;
  const bool is_kv = (id < G0B);
  int mt = 0, nt;
  const f16 *Abase, *Bbase;
  if (is_kv) {
    const int xcd = id & 7, l = id >> 3;   // 1088 = 8 * 136, bijective
    mt = xcd * 17 + (l >> 3);              // 136 mt, 17 per XCD
    nt = l & 7;
    Abase = kv_in + (size_t)mt * 256 * DIMD;
    Bbase = Wkv16 + (size_t)nt * 256 * DIMD;
  } else {
    const int id2 = id - G0B;
    const int bq = id2 >> 2;               // batch 0..7
    nt = id2 & 3;
    Abase = kv_in + ((size_t)(bq * LTOT + N1)) * DIMD;
    Bbase = Wq16 + (size_t)nt * 256 * DIMD;
  }
  __shared__ alignas(16) f16 As[2][2][128 * 64];
  __shared__ alignas(16) f16 Bs[2][2][128 * 64];
  const int tid = threadIdx.x;
  const int wave = tid >> 6, lane = tid & 63;
  const int wrow = wave >> 2, wcol = wave & 3;
  const int r16 = lane & 15, g8i = lane >> 4, q4 = (lane >> 4) * 4;
  const int xk = r16 & 7;
  const int t8 = tid >> 3, c8 = tid & 7;
  f32x4_t acc[8][4] = {};
  f16x8_t aF[4][2], b0F[2][2], b1F[2][2];

  // hoisted per-thread source bases (swizzled col is j-invariant: t8&7)
  const int col8 = (c8 ^ (t8 & 7)) * 8;
  const f16* Asrc = Abase + (size_t)t8 * DIMD + col8;
  const f16* Bsrc = Bbase + (size_t)((t8 >> 5) * 64 + (t8 & 31)) * DIMD + col8;

  auto stageA = [&](int kt, int buf, int mh) {
#pragma unroll
    for (int j = 0; j < 2; j++)
      g2l16(Asrc + (size_t)(j * 128 + mh * 64) * DIMD + kt * 64,
            &As[buf][mh][(j * 512 + wave * 64) * 8]);
  };
  auto stageB = [&](int kt, int buf, int nh) {
#pragma unroll
    for (int j = 0; j < 2; j++)
      g2l16(Bsrc + (size_t)(j * 128 + nh * 32) * DIMD + kt * 64,
            &Bs[buf][nh][(j * 512 + wave * 64) * 8]);
  };

  // prologue: K0 all 4 halves + K1 {A0, B1}; vmcnt(4) => K0 landed
  stageA(0, 0, 0); stageB(0, 0, 1); stageA(0, 0, 1); stageB(0, 0, 0);
  stageA(1, 1, 0); stageB(1, 1, 1);
  VM4; BARR;

#pragma unroll 1
  for (int it = 0; it < 8; ++it) {
    const int kA = 2 * it + 1;
    const int kB = (2 * it + 2 > 15) ? 15 : 2 * it + 2;  // clamp: dead-staged
    const int kC = (2 * it + 3 > 15) ? 15 : 2 * it + 3;
    // p0: quadrant (0,0) of buf0
    DS_A(0, 0); DS_B(b0F, 0, 0);
    stageA(kA, 1, 1);
    BARR; MFMA16(0, 0, b0F);
    // p1: (0,1)
    DS_B(b1F, 0, 1);
    stageB(kA, 1, 0);
    BARR; MFMA16(0, 1, b1F);
    // p2: (1,1)
    DS_A(0, 1);
    stageA(kB, 0, 0);
    BARR; MFMA16(1, 1, b1F);
    // p3: (1,0); vmcnt(4) publishes buf1 (K 2i+1) for p4-7
    stageB(kB, 0, 1);
    VM4;
    BARR; MFMA16(1, 0, b0F);
    // p4: (0,0) of buf1
    DS_A(1, 0); DS_B(b0F, 1, 0);
    stageA(kB, 0, 1);
    BARR; MFMA16(0, 0, b0F);
    // p5: (0,1)
    DS_B(b1F, 1, 1);
    stageB(kB, 0, 0);
    BARR; MFMA16(0, 1, b1F);
    // p6: (1,1)
    DS_A(1, 1);
    stageA(kC, 1, 0);
    BARR; MFMA16(1, 1, b1F);
    // p7: (1,0); vmcnt(4) publishes buf0 (K 2i+2) for next iter p0-3
    stageB(kC, 1, 1);
    VM4;
    BARR; MFMA16(1, 0, b0F);
  }
  asm volatile("s_waitcnt vmcnt(0)" ::: "memory");  // drain dead stages

  if (is_kv) {
    const int m0 = mt * 256;
    const int b = m0 / LTOT;
    const int n0 = m0 - b * LTOT;
    if (nt < 4) {  // k half: ((b*16+h)*4352 + n)*64 + d
#pragma unroll
      for (int ai = 0; ai < 8; ai++) {
        const int n_base = n0 + wrow * 128 + (ai >> 2) * 64 + (ai & 3) * 16 + q4;
#pragma unroll
        for (int bj = 0; bj < 4; bj++) {
          const int e = nt * 256 + wcol * 64 + (bj >> 1) * 32 + (bj & 1) * 16 + r16;
          const int h = e >> 6, d = e & 63;
          const size_t base = (size_t)(b * HEADS + h) * LTOT;
#pragma unroll
          for (int r = 0; r < 4; r++)
            kbuf[(base + n_base + r) * DH + d] = (f16)acc[ai][bj][r];
        }
      }
    } else {  // v half, transposed: ((b*16+h)*64 + d)*4352 + n
#pragma unroll
      for (int ai = 0; ai < 8; ai++) {
        const int n_base = n0 + wrow * 128 + (ai >> 2) * 64 + (ai & 3) * 16 + q4;
#pragma unroll
        for (int bj = 0; bj < 4; bj++) {
          const int e = (nt - 4) * 256 + wcol * 64 + (bj >> 1) * 32 + (bj & 1) * 16 + r16;
          const int h = e >> 6, d = e & 63;
          f16x4_t pk = {(f16)acc[ai][bj][0], (f16)acc[ai][bj][1],
                        (f16)acc[ai][bj][2], (f16)acc[ai][bj][3]};
          *(f16x4_t*)&vbuf[((size_t)(b * HEADS + h) * DH + d) * LTOT + n_base] = pk;
        }
      }
    }
  } else {  // q: ((b*16+h)*256 + n)*64 + d
    const int b = (id - G0B) >> 2;
#pragma unroll
    for (int ai = 0; ai < 8; ai++) {
      const int qn = wrow * 128 + (ai >> 2) * 64 + (ai & 3) * 16 + q4;
#pragma unroll
      for (int bj = 0; bj < 4; bj++) {
        const int e = nt * 256 + wcol * 64 + (bj >> 1) * 32 + (bj & 1) * 16 + r16;
        const int h = e >> 6, d = e & 63;
#pragma unroll
        for (int r = 0; r < 4; r++)
          qbuf[((size_t)(b * HEADS + h) * N2 + qn + r) * DH + d] = (f16)acc[ai][bj][r];
      }
    }
  }
}

// ---------------------------------------------------------------------------
// Kernel 3: out GEMM -> f32 d_out. R6: 64x64 tiles, grid 512 (32mt x 16nt),
// 256 threads / 4 waves (2x2, wave tile 32x32), LDS 16KB -> 2+ blocks/CU for
// cross-block latency hiding. BK=32, dbuf, T2 swizzle, counted vmcnt(2).
// ---------------------------------------------------------------------------
__global__ __launch_bounds__(256) void gemm_out(
    const f16* __restrict__ A0, const f16* __restrict__ BT,
    float* __restrict__ outp) {
  const int id = blockIdx.x;
  const int mt = id >> 4, nt = id & 15;   // 32 x 16
  const f16* Abase = A0 + (size_t)mt * 64 * DIMD;
  const f16* Bbase = BT + (size_t)nt * 64 * DIMD;
  __shared__ alignas(16) f16 As[2][64 * 32];
  __shared__ alignas(16) f16 Bs[2][64 * 32];
  const int tid = threadIdx.x;
  const int wave = tid >> 6, lane = tid & 63;
  const int wr = wave >> 1, wc = wave & 1;
  const int r16 = lane & 15, q4 = (lane >> 4) * 4;
  const int g8sw = (((lane >> 4) ^ ((r16 >> 1) & 3)) * 8);
  const int tq = tid >> 2;                 // row 0..63
  const int colx = (((tid & 3) ^ ((tq >> 1) & 3)) * 8);  // inverse-swz source
  const f16* Asrc = Abase + (size_t)tq * DIMD + colx;
  const f16* Bsrc = Bbase + (size_t)tq * DIMD + colx;
  f32x4_t acc[2][2] = {};

  auto stage = [&](int kt, int buf) {
    g2l16(Asrc + kt * 32, &As[buf][wave * 512]);
    g2l16(Bsrc + kt * 32, &Bs[buf][wave * 512]);
  };
  stage(0, 0);
#pragma unroll 1
  for (int kt = 0; kt < 32; ++kt) {
    const int cur = kt & 1;
    stage(kt + 1 < 32 ? kt + 1 : 31, cur ^ 1);  // tail: dead-stage
    asm volatile("s_waitcnt vmcnt(2)" ::: "memory");  // tile kt landed
    asm volatile("s_barrier" ::: "memory");
    f16x8_t a[2], bf[2];
#pragma unroll
    for (int i = 0; i < 2; i++)
      a[i] = *(const f16x8_t*)&As[cur][(wr * 32 + i * 16 + r16) * 32 + g8sw];
#pragma unroll
    for (int j = 0; j < 2; j++)
      bf[j] = *(const f16x8_t*)&Bs[cur][(wc * 32 + j * 16 + r16) * 32 + g8sw];
#pragma unroll
    for (int i = 0; i < 2; i++)
#pragma unroll
      for (int j = 0; j < 2; j++)
        acc[i][j] = __builtin_amdgcn_mfma_f32_16x16x32_f16(a[i], bf[j], acc[i][j], 0, 0, 0);
    asm volatile("s_barrier" ::: "memory");  // reads done before next re-stage
  }
  asm volatile("s_waitcnt vmcnt(0)" ::: "memory");

  const int m0 = mt * 64, n0 = nt * 64;
#pragma unroll
  for (int i = 0; i < 2; i++) {
#pragma unroll
    for (int j = 0; j < 2; j++) {
      const int col = n0 + wc * 32 + j * 16 + r16;
#pragma unroll
      for (int r = 0; r < 4; r++)
        outp[(size_t)(m0 + wr * 32 + i * 16 + q4 + r) * DIMD + col] = acc[i][j][r];
    }
  }
}

// ---------------------------------------------------------------------------
// Kernel 4: flash attention. R6: q-tile 128->64, 256 threads / 4 waves,
// grid 512 -> 2 blocks/CU (LDS 41KB) so independent blocks cover each other's
// barrier/vmcnt stalls. Per wave: unchanged 16 q-rows. Stage: 4 g2l16/wave
// (2 K + 2 V chunks); vmcnt scaled 2->4, prologue 4->8.
// Pair swizzle: bid, bid+128, +256, +384 share bh -> same XCD (128%8==0).
// ---------------------------------------------------------------------------
__global__ __launch_bounds__(256, 2) void attn_kernel(
    const f16* __restrict__ qbuf, const f16* __restrict__ kbuf,
    const f16* __restrict__ vbuf, f16* __restrict__ attn_out) {
  const int bh = blockIdx.x & 127;
  const int qt = blockIdx.x >> 7;          // 0..3, q-tile of 64 rows
  const int b = bh >> 4, h = bh & 15;
  const f16* qg = qbuf + ((size_t)bh * N2 + qt * 64) * DH;
  const f16* kg = kbuf + (size_t)bh * LTOT * DH;
  const f16* vg = vbuf + (size_t)bh * DH * LTOT;

  __shared__ alignas(16) f16 Ks[2][4096];  // 2 bufs x (2 d-panels x 64k x 32)
  __shared__ alignas(16) f16 Vs[2][4096];  // 2 bufs x (2 k-panels x 64d x 32)
  __shared__ alignas(16) f16 QP[4608];     // Q (4096, prologue) / P (per-wave)

  const int tid = threadIdx.x, wave = tid >> 6, lane = tid & 63;
  const int lrow = lane >> 2;
  const int r16 = lane & 15, g8 = (lane >> 4) * 8, q4 = (lane >> 4) * 4;
  const int lcol_sw = (((lane & 3) ^ ((lrow >> 1) & 3)) * 8);
  const int g8sw = (((lane >> 4) ^ ((r16 >> 1) & 3)) * 8);
  f16* Ps = &QP[wave * 1152];  // 16 q-rows x 72 halves, wave-private

  // prologue: stage Q (64 rows = 8 chunks, 2 per wave), source pre-swizzled
#pragma unroll
  for (int i = 0; i < 2; i++) {
    const int c = wave * 2 + i, s = c >> 2, rb = (c & 3) * 16;
    g2l16(qg + (size_t)(rb + lrow) * DH + s * 32 + lcol_sw, &QP[s * 2048 + rb * 32]);
  }
  auto stage = [&](int kt, int buf) {  // 4 g2l16/wave: 2 K + 2 V chunks
#pragma unroll
    for (int i = 0; i < 2; i++) {
      const int c = wave * 2 + i, s = c >> 2, rb = (c & 3) * 16;
      g2l16(kg + (size_t)(kt * ATILE + rb + lrow) * DH + s * 32 + lcol_sw,
            &Ks[buf][s * 2048 + rb * 32]);
      g2l16(vg + (size_t)(rb + lrow) * LTOT + kt * ATILE + s * 32 + lcol_sw,
            &Vs[buf][s * 2048 + rb * 32]);
    }
  };
  stage(0, 0);
  stage(1, 1);
  asm volatile("s_waitcnt vmcnt(8)" ::: "memory");  // Q (oldest 2) landed
  asm volatile("s_barrier" ::: "memory");
  f16x8_t bQ[2];
#pragma unroll
  for (int s = 0; s < 2; s++)
    bQ[s] = *(const f16x8_t*)&QP[s * 2048 + (wave * 16 + r16) * 32 + g8sw];
  asm volatile("s_waitcnt lgkmcnt(0)" ::: "memory");  // bQ in regs before P overlays Q

  f32x4_t oacc[4] = {};
  float mrow = -1e30f, lsum = 0.0f;
  const float SCL = 0.125f * 1.44269504089f;  // attn_scale^2 * log2(e)

  for (int kt = 0; kt < AITERS; kt++) {
    const int cur = kt & 1;
    asm volatile("s_waitcnt vmcnt(4)" ::: "memory");  // buf[cur] landed; next in flight
    asm volatile("s_barrier" ::: "memory");
    f32x4_t sacc[4] = {};
    __builtin_amdgcn_s_setprio(1);
#pragma unroll
    for (int s = 0; s < 2; s++) {
      f16x8_t aK[4];
#pragma unroll
      for (int i = 0; i < 4; i++)
        aK[i] = *(const f16x8_t*)&Ks[cur][s * 2048 + (i * 16 + r16) * 32 + g8sw];
#pragma unroll
      for (int i = 0; i < 4; i++)
        sacc[i] = __builtin_amdgcn_mfma_f32_16x16x32_f16(aK[i], bQ[s], sacc[i], 0, 0, 0);
    }
    __builtin_amdgcn_s_setprio(0);
    float vmax = -1e30f;
#pragma unroll
    for (int i = 0; i < 4; i++)
#pragma unroll
      for (int r = 0; r < 4; r++) vmax = fmaxf(vmax, sacc[i][r]);
    vmax = fmaxf(vmax, __shfl_xor(vmax, 16, 64));
    vmax = fmaxf(vmax, __shfl_xor(vmax, 32, 64));
    // T13 defer-max: only rescale when some row's max grew by >8 (log2 units).
    const float pm = SCL * vmax;
    if (!__all(pm <= mrow + 8.0f)) {
      const float m_new = fmaxf(mrow, pm);
      const float alpha = exp2f(mrow - m_new);
      lsum *= alpha;
#pragma unroll
      for (int id = 0; id < 4; id++) oacc[id] *= alpha;
      mrow = m_new;
    }
    float psum = 0.0f;
#pragma unroll
    for (int i = 0; i < 4; i++) {
      f16x4_t pk;
#pragma unroll
      for (int r = 0; r < 4; r++) {
        const float p = exp2f(SCL * sacc[i][r] - mrow);
        psum += p;
        pk[r] = (f16)p;
      }
      *(f16x4_t*)&Ps[r16 * 72 + i * 16 + q4] = pk;
    }
    psum += __shfl_xor(psum, 16, 64);
    psum += __shfl_xor(psum, 32, 64);
    lsum += psum;
    __builtin_amdgcn_s_setprio(1);
#pragma unroll
    for (int s2 = 0; s2 < 2; s2++) {
      f16x8_t aV[4];
#pragma unroll
      for (int id = 0; id < 4; id++)
        aV[id] = *(const f16x8_t*)&Vs[cur][s2 * 2048 + (id * 16 + r16) * 32 + g8sw];
      const f16x8_t bP = *(const f16x8_t*)&Ps[r16 * 72 + s2 * 32 + g8];
#pragma unroll
      for (int id = 0; id < 4; id++)
        oacc[id] = __builtin_amdgcn_mfma_f32_16x16x32_f16(aV[id], bP, oacc[id], 0, 0, 0);
    }
    __builtin_amdgcn_s_setprio(0);
    asm volatile("s_waitcnt lgkmcnt(0)" ::: "memory");
    asm volatile("s_barrier" ::: "memory");
    if (kt + 2 < AITERS) stage(kt + 2, cur);
  }
  const float inv = 1.0f / lsum;
  const int q = qt * 64 + wave * 16 + r16;
  const size_t rowbase = ((size_t)(b * N2 + q)) * DIMD + h * DH;
#pragma unroll
  for (int id = 0; id < 4; id++) {
    f16x4_t pk;
#pragma unroll
    for (int r = 0; r < 4; r++) pk[r] = (f16)(oacc[id][r] * inv);
    *(f16x4_t*)&attn_out[rowbase + id * 16 + q4] = pk;
  }
}

// ---------------------------------------------------------------------------
extern "C" void kernel_launch(void* const* d_in, const int* in_sizes, int n_in,
                              void* d_out, int out_size, void* d_ws, size_t ws_size,
                              hipStream_t stream) {
  const float* x     = (const float*)d_in[0];
  const float* lat   = (const float*)d_in[1];
  const float* shift = (const float*)d_in[2];
  const float* scale = (const float*)d_in[3];
  const float* ln1w  = (const float*)d_in[4];
  const float* ln1b  = (const float*)d_in[5];
  const float* ln2w  = (const float*)d_in[6];
  const float* ln2b  = (const float*)d_in[7];
  const float* Wq    = (const float*)d_in[8];
  const float* Wkv   = (const float*)d_in[9];
  const float* Wo    = (const float*)d_in[10];
  float* outp = (float*)d_out;

  char* ws = (char*)d_ws;
  f16* kv_in = (f16*)ws;                 ws += (size_t)MKV * DIMD * 2;          // 68 MB
  f16* Wq16  = (f16*)ws;                 ws += (size_t)1024 * 1024 * 2;         // 2 MB
  f16* Wkv16 = (f16*)ws;                 ws += (size_t)2048 * 1024 * 2;         // 4 MB
  f16* Wo16  = (f16*)ws;                 ws += (size_t)1024 * 1024 * 2;         // 2 MB
  f16* qbuf  = (f16*)ws;                 ws += (size_t)B_SZ * HEADS * N2 * DH * 2;   // 4 MB
  f16* kbuf  = (f16*)ws;                 ws += (size_t)B_SZ * HEADS * LTOT * DH * 2; // 68 MB
  f16* vbuf  = (f16*)ws;                 ws += (size_t)B_SZ * HEADS * LTOT * DH * 2; // 68 MB
  f16* aout  = (f16*)ws;                 ws += (size_t)B_SZ * N2 * DIMD * 2;         // 4 MB

  prep_kernel<<<dim3(MKV + 4096), dim3(256), 0, stream>>>(
      x, lat, shift, scale, ln1w, ln1b, ln2w, ln2b, Wq, Wkv, Wo,
      kv_in, Wq16, Wkv16, Wo16);
  gemm_pre<<<dim3(G0B + 32), dim3(512), 0, stream>>>(
      kv_in, Wkv16, Wq16, kbuf, vbuf, qbuf);
  attn_kernel<<<dim3(512), dim3(256), 0, stream>>>(qbuf, kbuf, vbuf, aout);
  gemm_out<<<dim3(512), dim3(256), 0, stream>>>(aout, Wo16, outp);
}